// Round 10
// baseline (190.180 us; speedup 1.0000x reference)
//
#include <hip/hip_runtime.h>
#include <hip/hip_bf16.h>
#include <cmath>

// Problem constants (fixed by reference)
#define NB   4      // batch
#define LQ   2048   // query len
#define SK   2048   // source len
#define DD   256    // in depth
#define HD   256    // hidden
#define FC   8      // heads
#define CH   32     // channels per head (HD/FC)
#define MHEAD 32    // NB*FC

// hh-filter margin: |f32dot - bf16dot| <= 2*2^-9 per side (unit rows) + slack
#define MARGIN 0.0085f
#define CAP    16   // candidate slots per row (avg ~1.2 with global threshold)

typedef float f32x16 __attribute__((ext_vector_type(16)));
typedef float f32x2  __attribute__((ext_vector_type(2)));
typedef short bf16x8 __attribute__((ext_vector_type(8)));
typedef unsigned short ushort8v __attribute__((ext_vector_type(8)));

__device__ inline unsigned short f32_to_bf16_bits(float v) {
    __hip_bfloat16 b = __float2bfloat16(v);   // round-to-nearest
    return __builtin_bit_cast(unsigned short, b);
}
__device__ inline unsigned int ord_encode(float v) {
    unsigned int u = __float_as_uint(v);
    return (u & 0x80000000u) ? ~u : (u | 0x80000000u);
}
__device__ inline float ord_decode(unsigned int e) {
    unsigned int u = (e & 0x80000000u) ? (e & 0x7fffffffu) : ~e;
    return __uint_as_float(u);
}

#define MFMA32(a, b, c) __builtin_amdgcn_mfma_f32_32x32x16_bf16(a, b, c, 0, 0, 0)

// ------------------------------------------------------------------
// Exact-f32 projection GEMM: q (W0, 4 n-tiles) + k-point (W1 point
// cols, 4 n-tiles). 64x64 tile, 4x4/thread, LDS dbuf, pk-fma.
// Per-acc-element FMA chain k-ascending -> bit-identical to the
// passing R7/R9 kernels (argmax path must stay bit-stable).
// ------------------------------------------------------------------
__global__ __launch_bounds__(256)
void proj_gemm_kernel(const float* __restrict__ x0, const float* __restrict__ x1,
                      const float* __restrict__ W0, const float* __restrict__ b0f,
                      const float* __restrict__ W1, const float* __restrict__ b1f,
                      float* __restrict__ xq, float* __restrict__ xk)
{
    __shared__ float As[2][16][68];
    __shared__ float Bs[2][16][64];
    const int nt  = blockIdx.x;        // 0..7 (wave-uniform branch)
    const bool is0 = (nt < 4);
    const float* A    = is0 ? x0 : x1;
    const float* B    = is0 ? W0 : W1;
    const float* bias = is0 ? b0f : b1f;
    const int NB_ = is0 ? HD : 2 * HD;   // B row stride
    const int bm = blockIdx.y * 64;
    const int K  = DD;

    const int tx = threadIdx.x & 15;
    const int ty = threadIdx.x >> 4;
    f32x2 acc2[4][2] = {};

    const int arow = threadIdx.x >> 2;           // 0..63
    const int akq  = (threadIdx.x & 3) << 2;     // 0,4,8,12
    const int bkr  = threadIdx.x >> 4;           // 0..15
    const int bnq  = (threadIdx.x & 15) << 2;    // 0..60
    const int bcol = is0 ? (nt * 64 + bnq)
                         : ((nt - 4) * 128 + ((bnq >> 5) << 6) + (bnq & 31));

    {
        const float4 a4 = *(const float4*)&A[(size_t)(bm + arow) * K + akq];
        const float4 b4 = *(const float4*)&B[(size_t)bkr * NB_ + bcol];
        As[0][akq + 0][arow] = a4.x;
        As[0][akq + 1][arow] = a4.y;
        As[0][akq + 2][arow] = a4.z;
        As[0][akq + 3][arow] = a4.w;
        *(float4*)&Bs[0][bkr][bnq] = b4;
    }
    __syncthreads();

    const int nchunk = K >> 4;   // 16
    float4 pa, pb;
    for (int c = 0; c < nchunk; ++c) {
        const int cur = c & 1;
        if (c + 1 < nchunk) {
            const int k0 = (c + 1) << 4;
            pa = *(const float4*)&A[(size_t)(bm + arow) * K + k0 + akq];
            pb = *(const float4*)&B[(size_t)(k0 + bkr) * NB_ + bcol];
        }
        #pragma unroll
        for (int kk = 0; kk < 16; ++kk) {
            const float4 a4 = *(const float4*)&As[cur][kk][ty << 2];
            const f32x2 b01 = *(const f32x2*)&Bs[cur][kk][tx << 2];
            const f32x2 b23 = *(const f32x2*)&Bs[cur][kk][(tx << 2) + 2];
            const float av[4] = {a4.x, a4.y, a4.z, a4.w};
            #pragma unroll
            for (int i = 0; i < 4; ++i) {
                const f32x2 aa = {av[i], av[i]};
                acc2[i][0] = __builtin_elementwise_fma(aa, b01, acc2[i][0]);
                acc2[i][1] = __builtin_elementwise_fma(aa, b23, acc2[i][1]);
            }
        }
        if (c + 1 < nchunk) {
            const int nxt = cur ^ 1;
            As[nxt][akq + 0][arow] = pa.x;
            As[nxt][akq + 1][arow] = pa.y;
            As[nxt][akq + 2][arow] = pa.z;
            As[nxt][akq + 3][arow] = pa.w;
            *(float4*)&Bs[nxt][bkr][bnq] = pb;
        }
        __syncthreads();
    }

    #pragma unroll
    for (int i = 0; i < 4; ++i) {
        const int row = bm + (ty << 2) + i;
        const int n = row >> 11, l = row & 2047;
        #pragma unroll
        for (int j = 0; j < 4; ++j) {
            const int cl = (tx << 2) + j;
            if (is0) {
                const int col = nt * 64 + cl;
                const float v = acc2[i][j >> 1][j & 1] + bias[col];
                const int f = col >> 5, cc = col & 31;
                xq[((((size_t)n * FC + f) * LQ) + l) * CH + cc] = v;
            } else {
                const int w = (nt - 4) * 128 + ((cl >> 5) << 6) + (cl & 31);
                const float v = acc2[i][j >> 1][j & 1] + bias[w];
                const int f = (nt - 4) * 2 + (cl >> 5), cc = cl & 31;
                xk[((((size_t)n * FC + f) * SK) + l) * CH + cc] = v;
            }
        }
    }
}

// ------------------------------------------------------------------
// Prep: x1 -> bf16 rows; Wm and W1-value cols -> bf16 B-frag swizzle.
// ------------------------------------------------------------------
__global__ __launch_bounds__(256)
void prep_kernel(const float* __restrict__ x1, const float* __restrict__ Wm,
                 const float* __restrict__ W1,
                 unsigned short* __restrict__ x1b,
                 unsigned short* __restrict__ wm_s,
                 unsigned short* __restrict__ wv_s)
{
    const int i = blockIdx.x * 256 + threadIdx.x;
    if (i < 262144) {
        const float4 a = *(const float4*)(x1 + (size_t)i * 8);
        const float4 b = *(const float4*)(x1 + (size_t)i * 8 + 4);
        ushort8v o;
        o[0] = f32_to_bf16_bits(a.x); o[1] = f32_to_bf16_bits(a.y);
        o[2] = f32_to_bf16_bits(a.z); o[3] = f32_to_bf16_bits(a.w);
        o[4] = f32_to_bf16_bits(b.x); o[5] = f32_to_bf16_bits(b.y);
        o[6] = f32_to_bf16_bits(b.z); o[7] = f32_to_bf16_bits(b.w);
        *(ushort8v*)(x1b + (size_t)i * 8) = o;
    } else if (i < 262144 + 65536) {
        const int j = i - 262144;
        const int k = j >> 8, n = j & 255;
        wm_s[(k >> 4) * 4096 + n * 16 + (k & 15)] = f32_to_bf16_bits(Wm[k * 256 + n]);
    } else {
        const int j = i - 327680;
        const int k = j >> 8, v = j & 255;
        const int w = (v >> 5) * 64 + 32 + (v & 31);
        wv_s[(k >> 4) * 4096 + v * 16 + (k & 15)] = f32_to_bf16_bits(W1[k * 512 + w]);
    }
}

// ------------------------------------------------------------------
// Value projection via bf16 MFMA: x1v = x1 @ W1value + b1value.
// ------------------------------------------------------------------
__global__ __launch_bounds__(256)
void val_gemm_kernel(const unsigned short* __restrict__ x1b,
                     const unsigned short* __restrict__ wv_s,
                     const float* __restrict__ b1f, float* __restrict__ xv)
{
    const int wave = threadIdx.x >> 6;
    const int lane = threadIdx.x & 63;
    const int idx  = blockIdx.x * 4 + wave;
    const int mt   = idx >> 3;
    const int nt   = idx & 7;
    const int col  = lane & 31;
    const int g8   = (lane >> 5) * 8;

    const unsigned short* aptr = x1b + (size_t)(mt * 32 + col) * 256 + g8;
    const unsigned short* bptr = wv_s + nt * 32 * 16 + col * 16 + g8;

    f32x16 acc = {0.f, 0.f, 0.f, 0.f, 0.f, 0.f, 0.f, 0.f,
                  0.f, 0.f, 0.f, 0.f, 0.f, 0.f, 0.f, 0.f};
    #pragma unroll 4
    for (int kc = 0; kc < 16; ++kc) {
        const bf16x8 a = *(const bf16x8*)(aptr + kc * 16);
        const bf16x8 bfr = *(const bf16x8*)(bptr + (size_t)kc * 4096);
        acc = MFMA32(a, bfr, acc);
    }

    const int v = nt * 32 + col;
    const int f = v >> 5, c = v & 31;
    const float bias = b1f[f * 64 + 32 + c];
    #pragma unroll
    for (int r = 0; r < 16; ++r) {
        const int g = mt * 32 + (r & 3) + 8 * (r >> 2) + 4 * (lane >> 5);
        const int n = g >> 11, s = g & 2047;
        xv[((((size_t)n * FC + f) * SK) + s) * CH + c] = acc[r] + bias;
    }
}

// ------------------------------------------------------------------
// Combined: L2-normalize q+k rows in place (bit-identical to R2),
// emit bf16 hi copies, zero-init maxhh_u and cnt.
// ------------------------------------------------------------------
__global__ __launch_bounds__(256)
void norm_split_init_kernel(float* __restrict__ xq, unsigned short* __restrict__ qhi,
                            float* __restrict__ xk, unsigned short* __restrict__ khi,
                            const float* __restrict__ alpha,
                            unsigned int* __restrict__ maxhh_u, int* __restrict__ cnt)
{
    int r = blockIdx.x * blockDim.x + threadIdx.x;
    float* p;
    unsigned short* dhi;
    float sgn = 1.f;
    if (r < MHEAD * LQ) {
        maxhh_u[r] = 0u;      // 0 < any ord-encoded float
        cnt[r] = 0;
        p   = xq + (size_t)r * CH;
        dhi = qhi + (size_t)r * CH;
        if (alpha[0] < 0.f) sgn = -1.f;
    } else {
        r -= MHEAD * LQ;
        p   = xk + (size_t)r * CH;
        dhi = khi + (size_t)r * CH;
    }

    float4 v[8];
    float ss = 0.f;
    #pragma unroll
    for (int i = 0; i < 8; ++i) {
        v[i] = *(const float4*)(p + i * 4);
        ss = fmaf(v[i].x, v[i].x, ss);
        ss = fmaf(v[i].y, v[i].y, ss);
        ss = fmaf(v[i].z, v[i].z, ss);
        ss = fmaf(v[i].w, v[i].w, ss);
    }
    const float inv = sgn / fmaxf(sqrtf(ss), 1e-12f);

    ushort8v hb[4];
    #pragma unroll
    for (int i = 0; i < 8; ++i) {
        float4 w;
        w.x = v[i].x * inv; w.y = v[i].y * inv;
        w.z = v[i].z * inv; w.w = v[i].w * inv;
        *(float4*)(p + i * 4) = w;
        hb[i >> 1][(i & 1) * 4 + 0] = f32_to_bf16_bits(w.x);
        hb[i >> 1][(i & 1) * 4 + 1] = f32_to_bf16_bits(w.y);
        hb[i >> 1][(i & 1) * 4 + 2] = f32_to_bf16_bits(w.z);
        hb[i >> 1][(i & 1) * 4 + 3] = f32_to_bf16_bits(w.w);
    }
    #pragma unroll
    for (int i = 0; i < 4; ++i)
        *(ushort8v*)(dhi + i * 8) = hb[i];
}

// ------------------------------------------------------------------
// Pass A1 v3: 64 q-rows/wave (2 A-frag sets), one 32-row k-tile per
// iteration (4 MFMA, 2 independent acc chains), depth-2 prefetch.
// Grid: 32 heads * 8 qb(256 rows) * 4 sc = 1024 blocks, 4 waves.
// Global per-row hh max via ordered-uint atomicMax.
// ------------------------------------------------------------------
__global__ __launch_bounds__(256, 4)
void maxpass_kernel(const unsigned short* __restrict__ qhi,
                    const unsigned short* __restrict__ khi,
                    unsigned int* __restrict__ maxhh_u)
{
    const int b    = blockIdx.x;
    const int sc   = b & 3;
    const int qb   = (b >> 2) & 7;
    const int h    = b >> 5;
    const int wave = threadIdx.x >> 6;
    const int lane = threadIdx.x & 63;
    const int qbase = qb * 256 + wave * 64;
    const int col   = lane & 31;
    const int g8    = (lane >> 5) * 8;

    const size_t q0off = ((size_t)h * LQ + qbase + col) * CH + g8;
    const size_t q1off = q0off + (size_t)32 * CH;
    const bf16x8 a00 = *(const bf16x8*)(qhi + q0off);
    const bf16x8 a01 = *(const bf16x8*)(qhi + q0off + 16);
    const bf16x8 a10 = *(const bf16x8*)(qhi + q1off);
    const bf16x8 a11 = *(const bf16x8*)(qhi + q1off + 16);

    const unsigned short* kh = khi + ((size_t)h * SK + sc * 512) * CH;
    const size_t koff = (size_t)col * CH + g8;

    float m0[16], m1[16];
    #pragma unroll
    for (int r = 0; r < 16; ++r) { m0[r] = -INFINITY; m1[r] = -INFINITY; }

    bf16x8 t0a = *(const bf16x8*)(kh + koff);
    bf16x8 t0b = *(const bf16x8*)(kh + koff + 16);
    bf16x8 t1a = *(const bf16x8*)(kh + koff + 32 * CH);
    bf16x8 t1b = *(const bf16x8*)(kh + koff + 32 * CH + 16);

    #pragma unroll
    for (int st = 0; st < 16; ++st) {
        const bf16x8 ka = (st & 1) ? t1a : t0a;
        const bf16x8 kb = (st & 1) ? t1b : t0b;
        if (st + 2 < 16) {
            const size_t o = koff + (size_t)(st + 2) * 32 * CH;
            if (st & 1) { t1a = *(const bf16x8*)(kh + o); t1b = *(const bf16x8*)(kh + o + 16); }
            else        { t0a = *(const bf16x8*)(kh + o); t0b = *(const bf16x8*)(kh + o + 16); }
        }
        f32x16 c0 = {0.f, 0.f, 0.f, 0.f, 0.f, 0.f, 0.f, 0.f,
                     0.f, 0.f, 0.f, 0.f, 0.f, 0.f, 0.f, 0.f};
        f32x16 c1 = c0;
        c0 = MFMA32(a00, ka, c0);
        c1 = MFMA32(a10, ka, c1);
        c0 = MFMA32(a01, kb, c0);
        c1 = MFMA32(a11, kb, c1);
        #pragma unroll
        for (int r = 0; r < 16; ++r) {
            m0[r] = fmaxf(m0[r], c0[r]);
            m1[r] = fmaxf(m1[r], c1[r]);
        }
    }

    #pragma unroll
    for (int r = 0; r < 16; ++r) {
        float v0 = m0[r], v1 = m1[r];
        #pragma unroll
        for (int m = 16; m >= 1; m >>= 1) {
            v0 = fmaxf(v0, __shfl_xor(v0, m, 64));
            v1 = fmaxf(v1, __shfl_xor(v1, m, 64));
        }
        m0[r] = v0; m1[r] = v1;
    }
    if (col == 0) {
        const int rbase = h * LQ + qbase + 4 * (lane >> 5);
        #pragma unroll
        for (int r = 0; r < 16; ++r) {
            const int crow = (r & 3) + 8 * (r >> 2);
            atomicMax(&maxhh_u[rbase + crow], ord_encode(m0[r]));
            atomicMax(&maxhh_u[rbase + 32 + crow], ord_encode(m1[r]));
        }
    }
}

// ------------------------------------------------------------------
// Pass A2 v3: same scan structure; append s with hh >= globalmax-MARGIN.
// ------------------------------------------------------------------
__global__ __launch_bounds__(256, 4)
void candpass_kernel(const unsigned short* __restrict__ qhi,
                     const unsigned short* __restrict__ khi,
                     const unsigned int* __restrict__ maxhh_u,
                     int* __restrict__ cnt, int* __restrict__ cand)
{
    const int b    = blockIdx.x;
    const int sc   = b & 3;
    const int qb   = (b >> 2) & 7;
    const int h    = b >> 5;
    const int wave = threadIdx.x >> 6;
    const int lane = threadIdx.x & 63;
    const int qbase = qb * 256 + wave * 64;
    const int col   = lane & 31;
    const int g8    = (lane >> 5) * 8;

    const size_t q0off = ((size_t)h * LQ + qbase + col) * CH + g8;
    const size_t q1off = q0off + (size_t)32 * CH;
    const bf16x8 a00 = *(const bf16x8*)(qhi + q0off);
    const bf16x8 a01 = *(const bf16x8*)(qhi + q0off + 16);
    const bf16x8 a10 = *(const bf16x8*)(qhi + q1off);
    const bf16x8 a11 = *(const bf16x8*)(qhi + q1off + 16);

    const int rbase = h * LQ + qbase + 4 * (lane >> 5);
    float thr0[16], thr1[16];
    #pragma unroll
    for (int r = 0; r < 16; ++r) {
        const int crow = (r & 3) + 8 * (r >> 2);
        thr0[r] = ord_decode(maxhh_u[rbase + crow]) - MARGIN;
        thr1[r] = ord_decode(maxhh_u[rbase + 32 + crow]) - MARGIN;
    }

    const unsigned short* kh = khi + ((size_t)h * SK + sc * 512) * CH;
    const size_t koff = (size_t)col * CH + g8;
    const int sbase = sc * 512;

    bf16x8 t0a = *(const bf16x8*)(kh + koff);
    bf16x8 t0b = *(const bf16x8*)(kh + koff + 16);
    bf16x8 t1a = *(const bf16x8*)(kh + koff + 32 * CH);
    bf16x8 t1b = *(const bf16x8*)(kh + koff + 32 * CH + 16);

    #pragma unroll
    for (int st = 0; st < 16; ++st) {
        const bf16x8 ka = (st & 1) ? t1a : t0a;
        const bf16x8 kb = (st & 1) ? t1b : t0b;
        if (st + 2 < 16) {
            const size_t o = koff + (size_t)(st + 2) * 32 * CH;
            if (st & 1) { t1a = *(const bf16x8*)(kh + o); t1b = *(const bf16x8*)(kh + o + 16); }
            else        { t0a = *(const bf16x8*)(kh + o); t0b = *(const bf16x8*)(kh + o + 16); }
        }
        f32x16 c0 = {0.f, 0.f, 0.f, 0.f, 0.f, 0.f, 0.f, 0.f,
                     0.f, 0.f, 0.f, 0.f, 0.f, 0.f, 0.f, 0.f};
        f32x16 c1 = c0;
        c0 = MFMA32(a00, ka, c0);
        c1 = MFMA32(a10, ka, c1);
        c0 = MFMA32(a01, kb, c0);
        c1 = MFMA32(a11, kb, c1);

        unsigned int hit = 0u;
        #pragma unroll
        for (int r = 0; r < 16; ++r) {
            hit = (c0[r] >= thr0[r]) ? (hit | (1u << r)) : hit;
            hit = (c1[r] >= thr1[r]) ? (hit | (1u << (r + 16))) : hit;
        }
        if (hit) {
            const int s = sbase + st * 32 + col;
            #pragma unroll
            for (int r = 0; r < 16; ++r) {
                const int crow = (r & 3) + 8 * (r >> 2);
                if (hit & (1u << r)) {
                    const int row = rbase + crow;
                    const int slot = atomicAdd(&cnt[row], 1);
                    if (slot < CAP) cand[(size_t)row * CAP + slot] = s;
                }
                if (hit & (1u << (r + 16))) {
                    const int row = rbase + 32 + crow;
                    const int slot = atomicAdd(&cnt[row], 1);
                    if (slot < CAP) cand[(size_t)row * CAP + slot] = s;
                }
            }
        }
    }
}

// ------------------------------------------------------------------
// Pass B: exact f32 refine (chain bit-identical to R2) + sigmoid +
// gather + scale; writes new_x0 as bf16 for the MFMA output GEMM.
// ------------------------------------------------------------------
__global__ __launch_bounds__(256)
void refine_gather_kernel(const float* __restrict__ qn,
                          const float* __restrict__ kn,
                          const int* __restrict__ cnt, const int* __restrict__ cand,
                          const float* __restrict__ xv,
                          const float* __restrict__ alpha, const float* __restrict__ beta,
                          unsigned short* __restrict__ nxb)  // (4,2048,256) bf16
{
    const int r = blockIdx.x * blockDim.x + threadIdx.x;  // h*2048 + l
    const int h = r >> 11, l = r & 2047;

    float qr[CH];
    #pragma unroll
    for (int i = 0; i < 8; ++i) {
        const float4 v = *(const float4*)(qn + (size_t)r * CH + i * 4);
        qr[i * 4 + 0] = v.x; qr[i * 4 + 1] = v.y;
        qr[i * 4 + 2] = v.z; qr[i * 4 + 3] = v.w;
    }

    int m = cnt[r];
    if (m > CAP) m = CAP;
    float best = -INFINITY;
    int   bidx = 0x7fffffff;
    for (int j = 0; j < m; ++j) {
        const int s = cand[(size_t)r * CAP + j];
        const float4* k4 = (const float4*)(kn + ((size_t)h * SK + s) * CH);
        float p = 0.f;
        #pragma unroll
        for (int c = 0; c < 8; ++c) {
            const float4 kv = k4[c];
            p = fmaf(qr[c * 4 + 0], kv.x, p);
            p = fmaf(qr[c * 4 + 1], kv.y, p);
            p = fmaf(qr[c * 4 + 2], kv.z, p);
            p = fmaf(qr[c * 4 + 3], kv.w, p);
        }
        if (p > best || (p == best && s < bidx)) { best = p; bidx = s; }
    }
    if (bidx == 0x7fffffff) bidx = 0;   // unreachable guard

    const float a = alpha[0], be = beta[0];
    float tv;
    int idx = bidx;
    if (a == 0.f) { idx = 0; tv = be; }
    else          { tv = fmaf(fabsf(a), best, be); }
    float val;
    if (tv >= 0.f) val = 1.f / (1.f + expf(-tv));
    else           { const float e = expf(tv); val = e / (1.f + e); }

    const float4* vr = (const float4*)(xv + ((size_t)h * SK + idx) * CH);
    const int n = h >> 3, f = h & 7;
    unsigned short* out = nxb + (((size_t)n * LQ + l) * (FC * CH)) + f * CH;
    #pragma unroll
    for (int i = 0; i < 8; ++i) {
        const float4 w = vr[i];
        ushort8v o;
        o[0] = f32_to_bf16_bits(w.x * val);
        o[1] = f32_to_bf16_bits(w.y * val);
        o[2] = f32_to_bf16_bits(w.z * val);
        o[3] = f32_to_bf16_bits(w.w * val);
        *(unsigned long long*)(out + i * 4) = __builtin_bit_cast(unsigned long long,
            *(const ulong1*)&o);
    }
}

// ------------------------------------------------------------------
// K6: out = nx(bf16) @ Wm(bf16 swizzled) + bm, f32 out. MFMA 32x32.
// ------------------------------------------------------------------
__global__ __launch_bounds__(256)
void gemm_out_mfma_kernel(const unsigned short* __restrict__ nxb,
                          const unsigned short* __restrict__ wm_s,
                          const float* __restrict__ bm, float* __restrict__ out)
{
    const int wave = threadIdx.x >> 6;
    const int lane = threadIdx.x & 63;
    const int idx  = blockIdx.x * 4 + wave;
    const int mt   = idx >> 3;
    const int nt   = idx & 7;
    const int col  = lane & 31;
    const int g8   = (lane >> 5) * 8;

    const unsigned short* aptr = nxb + (size_t)(mt * 32 + col) * 256 + g8;
    const unsigned short* bptr = wm_s + nt * 32 * 16 + col * 16 + g8;

    f32x16 acc = {0.f, 0.f, 0.f, 0.f, 0.f, 0.f, 0.f, 0.f,
                  0.f, 0.f, 0.f, 0.f, 0.f, 0.f, 0.f, 0.f};
    #pragma unroll 4
    for (int kc = 0; kc < 16; ++kc) {
        const bf16x8 a = *(const bf16x8*)(aptr + kc * 16);
        const bf16x8 bfr = *(const bf16x8*)(bptr + (size_t)kc * 4096);
        acc = MFMA32(a, bfr, acc);
    }

    const int n0 = nt * 32;
    const float bias = bm[n0 + col];
    #pragma unroll
    for (int r = 0; r < 16; ++r) {
        const int row = mt * 32 + (r & 3) + 8 * (r >> 2) + 4 * (lane >> 5);
        out[(size_t)row * 256 + n0 + col] = acc[r] + bias;
    }
}

// ------------------------------------------------------------------
extern "C" void kernel_launch(void* const* d_in, const int* in_sizes, int n_in,
                              void* d_out, int out_size, void* d_ws, size_t ws_size,
                              hipStream_t stream)
{
    const float* x0 = (const float*)d_in[0];
    const float* x1 = (const float*)d_in[1];
    const float* W0 = (const float*)d_in[2];
    const float* b0 = (const float*)d_in[3];
    const float* W1 = (const float*)d_in[4];
    const float* b1 = (const float*)d_in[5];
    const float* Wm = (const float*)d_in[6];
    const float* bm = (const float*)d_in[7];
    const float* alpha = (const float*)d_in[8];
    const float* beta  = (const float*)d_in[9];
    float* out = (float*)d_out;

    char* ws = (char*)d_ws;
    const size_t MB = 1024ull * 1024ull;
    float* x0q = (float*)(ws + 0);          // (32,2048,32) f32, normalized in place
    float* x1k = (float*)(ws + 8 * MB);     // (32,2048,32) f32, normalized in place
    float* x1v = (float*)(ws + 16 * MB);    // (32,2048,32) f32 values
    unsigned short* qhi = (unsigned short*)(ws + 24 * MB);  // 4MB (dead after scan)
    unsigned short* khi = (unsigned short*)(ws + 28 * MB);  // 4MB
    unsigned short* x1b = (unsigned short*)(ws + 32 * MB);  // 4MB (dead after valgemm)
    int* cand = (int*)(ws + 32 * MB);       // 4MB CAP16 (reuses x1b; valgemm reads
                                            // x1b before candpass writes cand)
    unsigned int* maxhh_u = (unsigned int*)(ws + 36 * MB);          // 256KB
    int* cnt  = (int*)(ws + 36 * MB + 256 * 1024);                  // 256KB
    unsigned short* wm_s = (unsigned short*)(ws + 36 * MB + 512 * 1024); // 128KB
    unsigned short* wv_s = (unsigned short*)(ws + 36 * MB + 640 * 1024); // 128KB
    unsigned short* nxb  = (unsigned short*)(ws + 24 * MB); // reuse qhi region

    const int Mrows = NB * LQ;   // 8192

    // 1) exact-f32 projections: q + k-point (argmax path, bit-stable)
    proj_gemm_kernel<<<dim3(8, Mrows / 64), 256, 0, stream>>>(
        x0, x1, W0, b0, W1, b1, x0q, x1k);
    // 2) preps: x1->bf16, Wm & W1-value -> swizzled bf16
    prep_kernel<<<1536, 256, 0, stream>>>(x1, Wm, W1, x1b, wm_s, wv_s);
    // 3) value projection via bf16 MFMA
    val_gemm_kernel<<<512, 256, 0, stream>>>(x1b, wv_s, b1, x1v);
    // 4) normalize q+k in place + bf16 hi copies + zero maxhh/cnt
    norm_split_init_kernel<<<(2 * MHEAD * LQ) / 256, 256, 0, stream>>>(
        x0q, qhi, x1k, khi, alpha, maxhh_u, cnt);
    // 5) global hh max (64 q/wave, depth-2 prefetch)
    maxpass_kernel<<<1024, 256, 0, stream>>>(qhi, khi, maxhh_u);
    // 6) candidate collection vs global threshold
    candpass_kernel<<<1024, 256, 0, stream>>>(qhi, khi, maxhh_u, cnt, cand);
    // 7) exact refine + sigmoid + gather + scale -> bf16 nx
    refine_gather_kernel<<<(MHEAD * LQ) / 256, 256, 0, stream>>>(
        x0q, x1k, cnt, cand, x1v, alpha, beta, nxb);
    // 8) out = nx @ Wm + bm via bf16 MFMA
    gemm_out_mfma_kernel<<<512, 256, 0, stream>>>(nxb, wm_s, bm, out);
}

// Round 11
// 152.295 us; speedup vs baseline: 1.2488x; 1.2488x over previous
//
#include <hip/hip_runtime.h>
#include <hip/hip_bf16.h>
#include <cmath>

// Problem constants (fixed by reference)
#define NB   4      // batch
#define LQ   2048   // query len
#define SK   2048   // source len
#define DD   256    // in depth
#define HD   256    // hidden
#define FC   8      // heads
#define CH   32     // channels per head (HD/FC)
#define MHEAD 32    // NB*FC

// hh-filter margin: |f32dot - bf16dot| <= 2*2^-9 per side (unit rows) + slack
#define MARGIN 0.0085f
#define CAP    16   // candidate slots per row (avg ~1.2 with global threshold)

typedef float f32x16 __attribute__((ext_vector_type(16)));
typedef float f32x2  __attribute__((ext_vector_type(2)));
typedef short bf16x8 __attribute__((ext_vector_type(8)));
typedef unsigned short ushort8v __attribute__((ext_vector_type(8)));

__device__ inline unsigned short f32_to_bf16_bits(float v) {
    __hip_bfloat16 b = __float2bfloat16(v);   // round-to-nearest
    return __builtin_bit_cast(unsigned short, b);
}
__device__ inline unsigned int ord_encode(float v) {
    unsigned int u = __float_as_uint(v);
    return (u & 0x80000000u) ? ~u : (u | 0x80000000u);
}
__device__ inline float ord_decode(unsigned int e) {
    unsigned int u = (e & 0x80000000u) ? (e & 0x7fffffffu) : ~e;
    return __uint_as_float(u);
}

#define MFMA32(a, b, c) __builtin_amdgcn_mfma_f32_32x32x16_bf16(a, b, c, 0, 0, 0)

// ------------------------------------------------------------------
// Exact-f32 projection GEMM: q (W0, 4 n-tiles) + k-point (W1 point
// cols, 4 n-tiles). 64x64 tile, 4x4/thread, LDS dbuf, pk-fma.
// Per-acc-element FMA chain k-ascending -> bit-identical to the
// passing R7/R9/R10 kernels (argmax path must stay bit-stable).
// ------------------------------------------------------------------
__global__ __launch_bounds__(256)
void proj_gemm_kernel(const float* __restrict__ x0, const float* __restrict__ x1,
                      const float* __restrict__ W0, const float* __restrict__ b0f,
                      const float* __restrict__ W1, const float* __restrict__ b1f,
                      float* __restrict__ xq, float* __restrict__ xk)
{
    __shared__ float As[2][16][68];
    __shared__ float Bs[2][16][64];
    const int nt  = blockIdx.x;        // 0..7 (wave-uniform branch)
    const bool is0 = (nt < 4);
    const float* A    = is0 ? x0 : x1;
    const float* B    = is0 ? W0 : W1;
    const float* bias = is0 ? b0f : b1f;
    const int NB_ = is0 ? HD : 2 * HD;   // B row stride
    const int bm = blockIdx.y * 64;
    const int K  = DD;

    const int tx = threadIdx.x & 15;
    const int ty = threadIdx.x >> 4;
    f32x2 acc2[4][2] = {};

    const int arow = threadIdx.x >> 2;           // 0..63
    const int akq  = (threadIdx.x & 3) << 2;     // 0,4,8,12
    const int bkr  = threadIdx.x >> 4;           // 0..15
    const int bnq  = (threadIdx.x & 15) << 2;    // 0..60
    const int bcol = is0 ? (nt * 64 + bnq)
                         : ((nt - 4) * 128 + ((bnq >> 5) << 6) + (bnq & 31));

    {
        const float4 a4 = *(const float4*)&A[(size_t)(bm + arow) * K + akq];
        const float4 b4 = *(const float4*)&B[(size_t)bkr * NB_ + bcol];
        As[0][akq + 0][arow] = a4.x;
        As[0][akq + 1][arow] = a4.y;
        As[0][akq + 2][arow] = a4.z;
        As[0][akq + 3][arow] = a4.w;
        *(float4*)&Bs[0][bkr][bnq] = b4;
    }
    __syncthreads();

    const int nchunk = K >> 4;   // 16
    float4 pa, pb;
    for (int c = 0; c < nchunk; ++c) {
        const int cur = c & 1;
        if (c + 1 < nchunk) {
            const int k0 = (c + 1) << 4;
            pa = *(const float4*)&A[(size_t)(bm + arow) * K + k0 + akq];
            pb = *(const float4*)&B[(size_t)(k0 + bkr) * NB_ + bcol];
        }
        #pragma unroll
        for (int kk = 0; kk < 16; ++kk) {
            const float4 a4 = *(const float4*)&As[cur][kk][ty << 2];
            const f32x2 b01 = *(const f32x2*)&Bs[cur][kk][tx << 2];
            const f32x2 b23 = *(const f32x2*)&Bs[cur][kk][(tx << 2) + 2];
            const float av[4] = {a4.x, a4.y, a4.z, a4.w};
            #pragma unroll
            for (int i = 0; i < 4; ++i) {
                const f32x2 aa = {av[i], av[i]};
                acc2[i][0] = __builtin_elementwise_fma(aa, b01, acc2[i][0]);
                acc2[i][1] = __builtin_elementwise_fma(aa, b23, acc2[i][1]);
            }
        }
        if (c + 1 < nchunk) {
            const int nxt = cur ^ 1;
            As[nxt][akq + 0][arow] = pa.x;
            As[nxt][akq + 1][arow] = pa.y;
            As[nxt][akq + 2][arow] = pa.z;
            As[nxt][akq + 3][arow] = pa.w;
            *(float4*)&Bs[nxt][bkr][bnq] = pb;
        }
        __syncthreads();
    }

    #pragma unroll
    for (int i = 0; i < 4; ++i) {
        const int row = bm + (ty << 2) + i;
        const int n = row >> 11, l = row & 2047;
        #pragma unroll
        for (int j = 0; j < 4; ++j) {
            const int cl = (tx << 2) + j;
            if (is0) {
                const int col = nt * 64 + cl;
                const float v = acc2[i][j >> 1][j & 1] + bias[col];
                const int f = col >> 5, cc = col & 31;
                xq[((((size_t)n * FC + f) * LQ) + l) * CH + cc] = v;
            } else {
                const int w = (nt - 4) * 128 + ((cl >> 5) << 6) + (cl & 31);
                const float v = acc2[i][j >> 1][j & 1] + bias[w];
                const int f = (nt - 4) * 2 + (cl >> 5), cc = cl & 31;
                xk[((((size_t)n * FC + f) * SK) + l) * CH + cc] = v;
            }
        }
    }
}

// ------------------------------------------------------------------
// Prep: x1 -> bf16 rows; Wm and W1-value cols -> bf16 B-frag swizzle.
// ------------------------------------------------------------------
__global__ __launch_bounds__(256)
void prep_kernel(const float* __restrict__ x1, const float* __restrict__ Wm,
                 const float* __restrict__ W1,
                 unsigned short* __restrict__ x1b,
                 unsigned short* __restrict__ wm_s,
                 unsigned short* __restrict__ wv_s)
{
    const int i = blockIdx.x * 256 + threadIdx.x;
    if (i < 262144) {
        const float4 a = *(const float4*)(x1 + (size_t)i * 8);
        const float4 b = *(const float4*)(x1 + (size_t)i * 8 + 4);
        ushort8v o;
        o[0] = f32_to_bf16_bits(a.x); o[1] = f32_to_bf16_bits(a.y);
        o[2] = f32_to_bf16_bits(a.z); o[3] = f32_to_bf16_bits(a.w);
        o[4] = f32_to_bf16_bits(b.x); o[5] = f32_to_bf16_bits(b.y);
        o[6] = f32_to_bf16_bits(b.z); o[7] = f32_to_bf16_bits(b.w);
        *(ushort8v*)(x1b + (size_t)i * 8) = o;
    } else if (i < 262144 + 65536) {
        const int j = i - 262144;
        const int k = j >> 8, n = j & 255;
        wm_s[(k >> 4) * 4096 + n * 16 + (k & 15)] = f32_to_bf16_bits(Wm[k * 256 + n]);
    } else {
        const int j = i - 327680;
        const int k = j >> 8, v = j & 255;
        const int w = (v >> 5) * 64 + 32 + (v & 31);
        wv_s[(k >> 4) * 4096 + v * 16 + (k & 15)] = f32_to_bf16_bits(W1[k * 512 + w]);
    }
}

// ------------------------------------------------------------------
// Value projection via bf16 MFMA: x1v = x1 @ W1value + b1value.
// ------------------------------------------------------------------
__global__ __launch_bounds__(256)
void val_gemm_kernel(const unsigned short* __restrict__ x1b,
                     const unsigned short* __restrict__ wv_s,
                     const float* __restrict__ b1f, float* __restrict__ xv)
{
    const int wave = threadIdx.x >> 6;
    const int lane = threadIdx.x & 63;
    const int idx  = blockIdx.x * 4 + wave;
    const int mt   = idx >> 3;
    const int nt   = idx & 7;
    const int col  = lane & 31;
    const int g8   = (lane >> 5) * 8;

    const unsigned short* aptr = x1b + (size_t)(mt * 32 + col) * 256 + g8;
    const unsigned short* bptr = wv_s + nt * 32 * 16 + col * 16 + g8;

    f32x16 acc = {0.f, 0.f, 0.f, 0.f, 0.f, 0.f, 0.f, 0.f,
                  0.f, 0.f, 0.f, 0.f, 0.f, 0.f, 0.f, 0.f};
    #pragma unroll 4
    for (int kc = 0; kc < 16; ++kc) {
        const bf16x8 a = *(const bf16x8*)(aptr + kc * 16);
        const bf16x8 bfr = *(const bf16x8*)(bptr + (size_t)kc * 4096);
        acc = MFMA32(a, bfr, acc);
    }

    const int v = nt * 32 + col;
    const int f = v >> 5, c = v & 31;
    const float bias = b1f[f * 64 + 32 + c];
    #pragma unroll
    for (int r = 0; r < 16; ++r) {
        const int g = mt * 32 + (r & 3) + 8 * (r >> 2) + 4 * (lane >> 5);
        const int n = g >> 11, s = g & 2047;
        xv[((((size_t)n * FC + f) * SK) + s) * CH + c] = acc[r] + bias;
    }
}

// ------------------------------------------------------------------
// Combined: L2-normalize q+k rows in place (bit-identical to R2),
// emit bf16 hi copies, zero-init maxhh_u and cnt.
// ------------------------------------------------------------------
__global__ __launch_bounds__(256)
void norm_split_init_kernel(float* __restrict__ xq, unsigned short* __restrict__ qhi,
                            float* __restrict__ xk, unsigned short* __restrict__ khi,
                            const float* __restrict__ alpha,
                            unsigned int* __restrict__ maxhh_u, int* __restrict__ cnt)
{
    int r = blockIdx.x * blockDim.x + threadIdx.x;
    float* p;
    unsigned short* dhi;
    float sgn = 1.f;
    if (r < MHEAD * LQ) {
        maxhh_u[r] = 0u;      // 0 < any ord-encoded float
        cnt[r] = 0;
        p   = xq + (size_t)r * CH;
        dhi = qhi + (size_t)r * CH;
        if (alpha[0] < 0.f) sgn = -1.f;
    } else {
        r -= MHEAD * LQ;
        p   = xk + (size_t)r * CH;
        dhi = khi + (size_t)r * CH;
    }

    float4 v[8];
    float ss = 0.f;
    #pragma unroll
    for (int i = 0; i < 8; ++i) {
        v[i] = *(const float4*)(p + i * 4);
        ss = fmaf(v[i].x, v[i].x, ss);
        ss = fmaf(v[i].y, v[i].y, ss);
        ss = fmaf(v[i].z, v[i].z, ss);
        ss = fmaf(v[i].w, v[i].w, ss);
    }
    const float inv = sgn / fmaxf(sqrtf(ss), 1e-12f);

    ushort8v hb[4];
    #pragma unroll
    for (int i = 0; i < 8; ++i) {
        float4 w;
        w.x = v[i].x * inv; w.y = v[i].y * inv;
        w.z = v[i].z * inv; w.w = v[i].w * inv;
        *(float4*)(p + i * 4) = w;
        hb[i >> 1][(i & 1) * 4 + 0] = f32_to_bf16_bits(w.x);
        hb[i >> 1][(i & 1) * 4 + 1] = f32_to_bf16_bits(w.y);
        hb[i >> 1][(i & 1) * 4 + 2] = f32_to_bf16_bits(w.z);
        hb[i >> 1][(i & 1) * 4 + 3] = f32_to_bf16_bits(w.w);
    }
    #pragma unroll
    for (int i = 0; i < 4; ++i)
        *(ushort8v*)(dhi + i * 8) = hb[i];
}

// ------------------------------------------------------------------
// Pass A1 (R7-proven structure, s-split x8): 32 q-rows/wave, two
// 32-row k-tiles per iter, depth-2 prefetch, v_max3 fold. No spill
// (48-64 VGPR). Grid: 32 heads * 16 qb * 8 sc = 4096 blocks — at 64
// VGPR, 8 waves/SIMD fit: parallelism is the latency-hiding lever.
// ------------------------------------------------------------------
__global__ __launch_bounds__(256, 4)
void maxpass_kernel(const unsigned short* __restrict__ qhi,
                    const unsigned short* __restrict__ khi,
                    unsigned int* __restrict__ maxhh_u)
{
    const int b    = blockIdx.x;
    const int sc   = b & 7;          // 8 s-chunks of 256
    const int qb   = (b >> 3) & 15;
    const int h    = b >> 7;
    const int wave = threadIdx.x >> 6;
    const int lane = threadIdx.x & 63;
    const int qbase = qb * 128 + wave * 32;
    const int col   = lane & 31;
    const int g8    = (lane >> 5) * 8;

    const size_t qoff = ((size_t)h * LQ + qbase + col) * CH + g8;
    const bf16x8 ah0 = *(const bf16x8*)(qhi + qoff);
    const bf16x8 ah1 = *(const bf16x8*)(qhi + qoff + 16);

    const unsigned short* kh = khi + ((size_t)h * SK + sc * 256) * CH;
    const size_t koff = (size_t)col * CH + g8;

    float maxv[16];
    #pragma unroll
    for (int r = 0; r < 16; ++r) maxv[r] = -INFINITY;

    bf16x8 t0a = *(const bf16x8*)(kh + koff);
    bf16x8 t0b = *(const bf16x8*)(kh + koff + 16);
    bf16x8 t1a = *(const bf16x8*)(kh + koff + 32 * CH);
    bf16x8 t1b = *(const bf16x8*)(kh + koff + 32 * CH + 16);

    for (int sb = 0; sb < 8; sb += 2) {
        const bf16x8 c0a = t0a, c0b = t0b, c1a = t1a, c1b = t1b;
        if (sb + 2 < 8) {
            const size_t o = koff + (size_t)(sb + 2) * 32 * CH;
            t0a = *(const bf16x8*)(kh + o);
            t0b = *(const bf16x8*)(kh + o + 16);
            t1a = *(const bf16x8*)(kh + o + 32 * CH);
            t1b = *(const bf16x8*)(kh + o + 32 * CH + 16);
        }
        f32x16 c = {0.f, 0.f, 0.f, 0.f, 0.f, 0.f, 0.f, 0.f,
                    0.f, 0.f, 0.f, 0.f, 0.f, 0.f, 0.f, 0.f};
        c = MFMA32(ah0, c0a, c);
        c = MFMA32(ah1, c0b, c);
        f32x16 d = {0.f, 0.f, 0.f, 0.f, 0.f, 0.f, 0.f, 0.f,
                    0.f, 0.f, 0.f, 0.f, 0.f, 0.f, 0.f, 0.f};
        d = MFMA32(ah0, c1a, d);
        d = MFMA32(ah1, c1b, d);
        #pragma unroll
        for (int r = 0; r < 16; ++r)
            maxv[r] = fmaxf(maxv[r], fmaxf(c[r], d[r]));   // -> v_max3_f32
    }

    #pragma unroll
    for (int r = 0; r < 16; ++r) {
        float v = maxv[r];
        #pragma unroll
        for (int m = 16; m >= 1; m >>= 1)
            v = fmaxf(v, __shfl_xor(v, m, 64));
        maxv[r] = v;
    }
    if (col == 0) {
        const int rbase = h * LQ + qbase + 4 * (lane >> 5);
        #pragma unroll
        for (int r = 0; r < 16; ++r)
            atomicMax(&maxhh_u[rbase + (r & 3) + 8 * (r >> 2)], ord_encode(maxv[r]));
    }
}

// ------------------------------------------------------------------
// Pass A2 (R7-proven structure, s-split x8): append s with
// hh >= globalmax - MARGIN. Hit-mask fast path.
// ------------------------------------------------------------------
__global__ __launch_bounds__(256, 4)
void candpass_kernel(const unsigned short* __restrict__ qhi,
                     const unsigned short* __restrict__ khi,
                     const unsigned int* __restrict__ maxhh_u,
                     int* __restrict__ cnt, int* __restrict__ cand)
{
    const int b    = blockIdx.x;
    const int sc   = b & 7;
    const int qb   = (b >> 3) & 15;
    const int h    = b >> 7;
    const int wave = threadIdx.x >> 6;
    const int lane = threadIdx.x & 63;
    const int qbase = qb * 128 + wave * 32;
    const int col   = lane & 31;
    const int g8    = (lane >> 5) * 8;

    const size_t qoff = ((size_t)h * LQ + qbase + col) * CH + g8;
    const bf16x8 ah0 = *(const bf16x8*)(qhi + qoff);
    const bf16x8 ah1 = *(const bf16x8*)(qhi + qoff + 16);

    int   rows[16];
    float thr[16];
    {
        const int rbase = h * LQ + qbase + 4 * (lane >> 5);
        #pragma unroll
        for (int r = 0; r < 16; ++r) {
            rows[r] = rbase + (r & 3) + 8 * (r >> 2);
            thr[r]  = ord_decode(maxhh_u[rows[r]]) - MARGIN;
        }
    }

    const unsigned short* kh = khi + ((size_t)h * SK + sc * 256) * CH;
    const size_t koff = (size_t)col * CH + g8;
    const int sbase = sc * 256;

    bf16x8 t0a = *(const bf16x8*)(kh + koff);
    bf16x8 t0b = *(const bf16x8*)(kh + koff + 16);
    bf16x8 t1a = *(const bf16x8*)(kh + koff + 32 * CH);
    bf16x8 t1b = *(const bf16x8*)(kh + koff + 32 * CH + 16);

    for (int sb = 0; sb < 8; sb += 2) {
        const bf16x8 c0a = t0a, c0b = t0b, c1a = t1a, c1b = t1b;
        if (sb + 2 < 8) {
            const size_t o = koff + (size_t)(sb + 2) * 32 * CH;
            t0a = *(const bf16x8*)(kh + o);
            t0b = *(const bf16x8*)(kh + o + 16);
            t1a = *(const bf16x8*)(kh + o + 32 * CH);
            t1b = *(const bf16x8*)(kh + o + 32 * CH + 16);
        }
        f32x16 c = {0.f, 0.f, 0.f, 0.f, 0.f, 0.f, 0.f, 0.f,
                    0.f, 0.f, 0.f, 0.f, 0.f, 0.f, 0.f, 0.f};
        c = MFMA32(ah0, c0a, c);
        c = MFMA32(ah1, c0b, c);
        f32x16 d = {0.f, 0.f, 0.f, 0.f, 0.f, 0.f, 0.f, 0.f,
                    0.f, 0.f, 0.f, 0.f, 0.f, 0.f, 0.f, 0.f};
        d = MFMA32(ah0, c1a, d);
        d = MFMA32(ah1, c1b, d);

        unsigned int hit = 0u;
        #pragma unroll
        for (int r = 0; r < 16; ++r) {
            const float e = fmaxf(c[r], d[r]);
            hit = (e >= thr[r]) ? (hit | (1u << r)) : hit;
        }
        if (hit) {
            const int s0 = sbase + sb * 32 + col;
            #pragma unroll
            for (int r = 0; r < 16; ++r) {
                if (hit & (1u << r)) {
                    if (c[r] >= thr[r]) {
                        const int slot = atomicAdd(&cnt[rows[r]], 1);
                        if (slot < CAP) cand[(size_t)rows[r] * CAP + slot] = s0;
                    }
                    if (d[r] >= thr[r]) {
                        const int slot = atomicAdd(&cnt[rows[r]], 1);
                        if (slot < CAP) cand[(size_t)rows[r] * CAP + slot] = s0 + 32;
                    }
                }
            }
        }
    }
}

// ------------------------------------------------------------------
// Pass B: exact f32 refine (chain bit-identical to R2) + sigmoid +
// gather + scale; writes new_x0 as bf16 for the MFMA output GEMM.
// ------------------------------------------------------------------
__global__ __launch_bounds__(256)
void refine_gather_kernel(const float* __restrict__ qn,
                          const float* __restrict__ kn,
                          const int* __restrict__ cnt, const int* __restrict__ cand,
                          const float* __restrict__ xv,
                          const float* __restrict__ alpha, const float* __restrict__ beta,
                          unsigned short* __restrict__ nxb)  // (4,2048,256) bf16
{
    const int r = blockIdx.x * blockDim.x + threadIdx.x;  // h*2048 + l
    const int h = r >> 11, l = r & 2047;

    float qr[CH];
    #pragma unroll
    for (int i = 0; i < 8; ++i) {
        const float4 v = *(const float4*)(qn + (size_t)r * CH + i * 4);
        qr[i * 4 + 0] = v.x; qr[i * 4 + 1] = v.y;
        qr[i * 4 + 2] = v.z; qr[i * 4 + 3] = v.w;
    }

    int m = cnt[r];
    if (m > CAP) m = CAP;
    float best = -INFINITY;
    int   bidx = 0x7fffffff;
    for (int j = 0; j < m; ++j) {
        const int s = cand[(size_t)r * CAP + j];
        const float4* k4 = (const float4*)(kn + ((size_t)h * SK + s) * CH);
        float p = 0.f;
        #pragma unroll
        for (int c = 0; c < 8; ++c) {
            const float4 kv = k4[c];
            p = fmaf(qr[c * 4 + 0], kv.x, p);
            p = fmaf(qr[c * 4 + 1], kv.y, p);
            p = fmaf(qr[c * 4 + 2], kv.z, p);
            p = fmaf(qr[c * 4 + 3], kv.w, p);
        }
        if (p > best || (p == best && s < bidx)) { best = p; bidx = s; }
    }
    if (bidx == 0x7fffffff) bidx = 0;   // unreachable guard

    const float a = alpha[0], be = beta[0];
    float tv;
    int idx = bidx;
    if (a == 0.f) { idx = 0; tv = be; }
    else          { tv = fmaf(fabsf(a), best, be); }
    float val;
    if (tv >= 0.f) val = 1.f / (1.f + expf(-tv));
    else           { const float e = expf(tv); val = e / (1.f + e); }

    const float4* vr = (const float4*)(xv + ((size_t)h * SK + idx) * CH);
    const int n = h >> 3, f = h & 7;
    unsigned short* out = nxb + (((size_t)n * LQ + l) * (FC * CH)) + f * CH;
    #pragma unroll
    for (int i = 0; i < 8; ++i) {
        const float4 w = vr[i];
        ushort8v o;
        o[0] = f32_to_bf16_bits(w.x * val);
        o[1] = f32_to_bf16_bits(w.y * val);
        o[2] = f32_to_bf16_bits(w.z * val);
        o[3] = f32_to_bf16_bits(w.w * val);
        *(unsigned long long*)(out + i * 4) = __builtin_bit_cast(unsigned long long,
            *(const ulong1*)&o);
    }
}

// ------------------------------------------------------------------
// K6: out = nx(bf16) @ Wm(bf16 swizzled) + bm, f32 out. MFMA 32x32.
// ------------------------------------------------------------------
__global__ __launch_bounds__(256)
void gemm_out_mfma_kernel(const unsigned short* __restrict__ nxb,
                          const unsigned short* __restrict__ wm_s,
                          const float* __restrict__ bm, float* __restrict__ out)
{
    const int wave = threadIdx.x >> 6;
    const int lane = threadIdx.x & 63;
    const int idx  = blockIdx.x * 4 + wave;
    const int mt   = idx >> 3;
    const int nt   = idx & 7;
    const int col  = lane & 31;
    const int g8   = (lane >> 5) * 8;

    const unsigned short* aptr = nxb + (size_t)(mt * 32 + col) * 256 + g8;
    const unsigned short* bptr = wm_s + nt * 32 * 16 + col * 16 + g8;

    f32x16 acc = {0.f, 0.f, 0.f, 0.f, 0.f, 0.f, 0.f, 0.f,
                  0.f, 0.f, 0.f, 0.f, 0.f, 0.f, 0.f, 0.f};
    #pragma unroll 4
    for (int kc = 0; kc < 16; ++kc) {
        const bf16x8 a = *(const bf16x8*)(aptr + kc * 16);
        const bf16x8 bfr = *(const bf16x8*)(bptr + (size_t)kc * 4096);
        acc = MFMA32(a, bfr, acc);
    }

    const int n0 = nt * 32;
    const float bias = bm[n0 + col];
    #pragma unroll
    for (int r = 0; r < 16; ++r) {
        const int row = mt * 32 + (r & 3) + 8 * (r >> 2) + 4 * (lane >> 5);
        out[(size_t)row * 256 + n0 + col] = acc[r] + bias;
    }
}

// ------------------------------------------------------------------
extern "C" void kernel_launch(void* const* d_in, const int* in_sizes, int n_in,
                              void* d_out, int out_size, void* d_ws, size_t ws_size,
                              hipStream_t stream)
{
    const float* x0 = (const float*)d_in[0];
    const float* x1 = (const float*)d_in[1];
    const float* W0 = (const float*)d_in[2];
    const float* b0 = (const float*)d_in[3];
    const float* W1 = (const float*)d_in[4];
    const float* b1 = (const float*)d_in[5];
    const float* Wm = (const float*)d_in[6];
    const float* bm = (const float*)d_in[7];
    const float* alpha = (const float*)d_in[8];
    const float* beta  = (const float*)d_in[9];
    float* out = (float*)d_out;

    char* ws = (char*)d_ws;
    const size_t MB = 1024ull * 1024ull;
    float* x0q = (float*)(ws + 0);          // (32,2048,32) f32, normalized in place
    float* x1k = (float*)(ws + 8 * MB);     // (32,2048,32) f32, normalized in place
    float* x1v = (float*)(ws + 16 * MB);    // (32,2048,32) f32 values
    unsigned short* qhi = (unsigned short*)(ws + 24 * MB);  // 4MB (dead after scan)
    unsigned short* khi = (unsigned short*)(ws + 28 * MB);  // 4MB
    unsigned short* x1b = (unsigned short*)(ws + 32 * MB);  // 4MB (dead after valgemm)
    int* cand = (int*)(ws + 32 * MB);       // 4MB CAP16 (reuses x1b; valgemm reads
                                            // x1b before candpass writes cand)
    unsigned int* maxhh_u = (unsigned int*)(ws + 36 * MB);          // 256KB
    int* cnt  = (int*)(ws + 36 * MB + 256 * 1024);                  // 256KB
    unsigned short* wm_s = (unsigned short*)(ws + 36 * MB + 512 * 1024); // 128KB
    unsigned short* wv_s = (unsigned short*)(ws + 36 * MB + 640 * 1024); // 128KB
    unsigned short* nxb  = (unsigned short*)(ws + 24 * MB); // reuse qhi region

    const int Mrows = NB * LQ;   // 8192

    // 1) exact-f32 projections: q + k-point (argmax path, bit-stable)
    proj_gemm_kernel<<<dim3(8, Mrows / 64), 256, 0, stream>>>(
        x0, x1, W0, b0, W1, b1, x0q, x1k);
    // 2) preps: x1->bf16, Wm & W1-value -> swizzled bf16
    prep_kernel<<<1536, 256, 0, stream>>>(x1, Wm, W1, x1b, wm_s, wv_s);
    // 3) value projection via bf16 MFMA
    val_gemm_kernel<<<512, 256, 0, stream>>>(x1b, wv_s, b1, x1v);
    // 4) normalize q+k in place + bf16 hi copies + zero maxhh/cnt
    norm_split_init_kernel<<<(2 * MHEAD * LQ) / 256, 256, 0, stream>>>(
        x0q, qhi, x1k, khi, alpha, maxhh_u, cnt);
    // 5) global hh max (32 q/wave proven structure, s-split x8)
    maxpass_kernel<<<4096, 256, 0, stream>>>(qhi, khi, maxhh_u);
    // 6) candidate collection vs global threshold (s-split x8)
    candpass_kernel<<<4096, 256, 0, stream>>>(qhi, khi, maxhh_u, cnt, cand);
    // 7) exact refine + sigmoid + gather + scale -> bf16 nx
    refine_gather_kernel<<<(MHEAD * LQ) / 256, 256, 0, stream>>>(
        x0q, x1k, cnt, cand, x1v, alpha, beta, nxb);
    // 8) out = nx @ Wm + bm via bf16 MFMA
    gemm_out_mfma_kernel<<<512, 256, 0, stream>>>(nxb, wm_s, bm, out);
}

// Round 12
// 139.615 us; speedup vs baseline: 1.3622x; 1.0908x over previous
//
#include <hip/hip_runtime.h>
#include <hip/hip_bf16.h>
#include <cmath>

// Problem constants (fixed by reference)
#define NB   4      // batch
#define LQ   2048   // query len
#define SK   2048   // source len
#define DD   256    // in depth
#define HD   256    // hidden
#define FC   8      // heads
#define CH   32     // channels per head (HD/FC)
#define MHEAD 32    // NB*FC

// hh-filter margin: |f32dot - bf16dot| <= 2*2^-9 per side (unit rows) + slack
#define MARGIN 0.0085f
#define CAP    16   // candidate slots per row (avg ~1.2 with global threshold)

typedef float f32x16 __attribute__((ext_vector_type(16)));
typedef float f32x2  __attribute__((ext_vector_type(2)));
typedef short bf16x8 __attribute__((ext_vector_type(8)));
typedef unsigned short ushort8v __attribute__((ext_vector_type(8)));

__device__ inline unsigned short f32_to_bf16_bits(float v) {
    __hip_bfloat16 b = __float2bfloat16(v);   // round-to-nearest
    return __builtin_bit_cast(unsigned short, b);
}
__device__ inline unsigned int ord_encode(float v) {
    unsigned int u = __float_as_uint(v);
    return (u & 0x80000000u) ? ~u : (u | 0x80000000u);
}
__device__ inline float ord_decode(unsigned int e) {
    unsigned int u = (e & 0x80000000u) ? (e & 0x7fffffffu) : ~e;
    return __uint_as_float(u);
}

#define MFMA32(a, b, c) __builtin_amdgcn_mfma_f32_32x32x16_bf16(a, b, c, 0, 0, 0)

// ------------------------------------------------------------------
// Exact-f32 projection GEMM: q (W0, nt 0-3) + k-point (W1 point cols,
// nt 4-7). 64x64 tile, 4x4/thread, LDS dbuf, pk-fma. UNIFIED epilogue:
// both paths use f=(nt&3)*2+(cl>>5), cc=cl&31; only head-stride (32
// vs 64), B row stride, and base pointer differ (all wave-uniform).
// __launch_bounds__(256,7) caps VGPR<=73 (R11's 88 VGPR halved
// occupancy; R7's equivalent code needed 36 -> no spill risk).
// Per-acc-element FMA chain k-ascending -> bit-identical to R2/R7.
// ------------------------------------------------------------------
__global__ __launch_bounds__(256, 7)
void proj_gemm_kernel(const float* __restrict__ x0, const float* __restrict__ x1,
                      const float* __restrict__ W0, const float* __restrict__ b0f,
                      const float* __restrict__ W1, const float* __restrict__ b1f,
                      float* __restrict__ xq, float* __restrict__ xk)
{
    __shared__ float As[2][16][68];
    __shared__ float Bs[2][16][64];
    const int nt  = blockIdx.x;        // 0..7 (wave-uniform branch)
    const bool is0 = (nt < 4);
    const float* A    = is0 ? x0 : x1;
    const float* B    = is0 ? W0 : W1;
    const float* bias = is0 ? b0f : b1f;
    float* dst        = is0 ? xq : xk;
    const int NB_ = is0 ? HD : 2 * HD;   // B row stride
    const int hw  = is0 ? 32 : 64;       // per-head column stride in B/bias
    const int bm  = blockIdx.y * 64;
    const int K   = DD;

    const int tx = threadIdx.x & 15;
    const int ty = threadIdx.x >> 4;
    f32x2 acc2[4][2] = {};

    const int arow = threadIdx.x >> 2;           // 0..63
    const int akq  = (threadIdx.x & 3) << 2;     // 0,4,8,12
    const int bkr  = threadIdx.x >> 4;           // 0..15
    const int bnq  = (threadIdx.x & 15) << 2;    // 0..60
    const int fl   = (nt & 3) * 2 + (bnq >> 5);  // head of loaded cols
    const int bcol = fl * hw + (bnq & 31);

    {
        const float4 a4 = *(const float4*)&A[(size_t)(bm + arow) * K + akq];
        const float4 b4 = *(const float4*)&B[(size_t)bkr * NB_ + bcol];
        As[0][akq + 0][arow] = a4.x;
        As[0][akq + 1][arow] = a4.y;
        As[0][akq + 2][arow] = a4.z;
        As[0][akq + 3][arow] = a4.w;
        *(float4*)&Bs[0][bkr][bnq] = b4;
    }
    __syncthreads();

    const int nchunk = K >> 4;   // 16
    float4 pa, pb;
    for (int c = 0; c < nchunk; ++c) {
        const int cur = c & 1;
        if (c + 1 < nchunk) {
            const int k0 = (c + 1) << 4;
            pa = *(const float4*)&A[(size_t)(bm + arow) * K + k0 + akq];
            pb = *(const float4*)&B[(size_t)(k0 + bkr) * NB_ + bcol];
        }
        #pragma unroll
        for (int kk = 0; kk < 16; ++kk) {
            const float4 a4 = *(const float4*)&As[cur][kk][ty << 2];
            const f32x2 b01 = *(const f32x2*)&Bs[cur][kk][tx << 2];
            const f32x2 b23 = *(const f32x2*)&Bs[cur][kk][(tx << 2) + 2];
            const float av[4] = {a4.x, a4.y, a4.z, a4.w};
            #pragma unroll
            for (int i = 0; i < 4; ++i) {
                const f32x2 aa = {av[i], av[i]};
                acc2[i][0] = __builtin_elementwise_fma(aa, b01, acc2[i][0]);
                acc2[i][1] = __builtin_elementwise_fma(aa, b23, acc2[i][1]);
            }
        }
        if (c + 1 < nchunk) {
            const int nxt = cur ^ 1;
            As[nxt][akq + 0][arow] = pa.x;
            As[nxt][akq + 1][arow] = pa.y;
            As[nxt][akq + 2][arow] = pa.z;
            As[nxt][akq + 3][arow] = pa.w;
            *(float4*)&Bs[nxt][bkr][bnq] = pb;
        }
        __syncthreads();
    }

    #pragma unroll
    for (int i = 0; i < 4; ++i) {
        const int row = bm + (ty << 2) + i;
        const int n = row >> 11, l = row & 2047;
        #pragma unroll
        for (int j = 0; j < 4; ++j) {
            const int cl = (tx << 2) + j;
            const int f  = (nt & 3) * 2 + (cl >> 5);
            const int cc = cl & 31;
            const float v = acc2[i][j >> 1][j & 1] + bias[f * hw + cc];
            dst[((((size_t)n * FC + f) * LQ) + l) * CH + cc] = v;
        }
    }
}

// ------------------------------------------------------------------
// Prep: x1 -> bf16 rows; Wm and W1-value cols -> bf16 B-frag swizzle.
// ------------------------------------------------------------------
__global__ __launch_bounds__(256)
void prep_kernel(const float* __restrict__ x1, const float* __restrict__ Wm,
                 const float* __restrict__ W1,
                 unsigned short* __restrict__ x1b,
                 unsigned short* __restrict__ wm_s,
                 unsigned short* __restrict__ wv_s)
{
    const int i = blockIdx.x * 256 + threadIdx.x;
    if (i < 262144) {
        const float4 a = *(const float4*)(x1 + (size_t)i * 8);
        const float4 b = *(const float4*)(x1 + (size_t)i * 8 + 4);
        ushort8v o;
        o[0] = f32_to_bf16_bits(a.x); o[1] = f32_to_bf16_bits(a.y);
        o[2] = f32_to_bf16_bits(a.z); o[3] = f32_to_bf16_bits(a.w);
        o[4] = f32_to_bf16_bits(b.x); o[5] = f32_to_bf16_bits(b.y);
        o[6] = f32_to_bf16_bits(b.z); o[7] = f32_to_bf16_bits(b.w);
        *(ushort8v*)(x1b + (size_t)i * 8) = o;
    } else if (i < 262144 + 65536) {
        const int j = i - 262144;
        const int k = j >> 8, n = j & 255;
        wm_s[(k >> 4) * 4096 + n * 16 + (k & 15)] = f32_to_bf16_bits(Wm[k * 256 + n]);
    } else {
        const int j = i - 327680;
        const int k = j >> 8, v = j & 255;
        const int w = (v >> 5) * 64 + 32 + (v & 31);
        wv_s[(k >> 4) * 4096 + v * 16 + (k & 15)] = f32_to_bf16_bits(W1[k * 512 + w]);
    }
}

// ------------------------------------------------------------------
// Value projection via bf16 MFMA: x1v = x1 @ W1value + b1value.
// ------------------------------------------------------------------
__global__ __launch_bounds__(256)
void val_gemm_kernel(const unsigned short* __restrict__ x1b,
                     const unsigned short* __restrict__ wv_s,
                     const float* __restrict__ b1f, float* __restrict__ xv)
{
    const int wave = threadIdx.x >> 6;
    const int lane = threadIdx.x & 63;
    const int idx  = blockIdx.x * 4 + wave;
    const int mt   = idx >> 3;
    const int nt   = idx & 7;
    const int col  = lane & 31;
    const int g8   = (lane >> 5) * 8;

    const unsigned short* aptr = x1b + (size_t)(mt * 32 + col) * 256 + g8;
    const unsigned short* bptr = wv_s + nt * 32 * 16 + col * 16 + g8;

    f32x16 acc = {0.f, 0.f, 0.f, 0.f, 0.f, 0.f, 0.f, 0.f,
                  0.f, 0.f, 0.f, 0.f, 0.f, 0.f, 0.f, 0.f};
    #pragma unroll 4
    for (int kc = 0; kc < 16; ++kc) {
        const bf16x8 a = *(const bf16x8*)(aptr + kc * 16);
        const bf16x8 bfr = *(const bf16x8*)(bptr + (size_t)kc * 4096);
        acc = MFMA32(a, bfr, acc);
    }

    const int v = nt * 32 + col;
    const int f = v >> 5, c = v & 31;
    const float bias = b1f[f * 64 + 32 + c];
    #pragma unroll
    for (int r = 0; r < 16; ++r) {
        const int g = mt * 32 + (r & 3) + 8 * (r >> 2) + 4 * (lane >> 5);
        const int n = g >> 11, s = g & 2047;
        xv[((((size_t)n * FC + f) * SK) + s) * CH + c] = acc[r] + bias;
    }
}

// ------------------------------------------------------------------
// Combined: L2-normalize q+k rows in place (bit-identical to R2),
// emit bf16 hi copies, zero-init maxhh_u and cnt.
// ------------------------------------------------------------------
__global__ __launch_bounds__(256)
void norm_split_init_kernel(float* __restrict__ xq, unsigned short* __restrict__ qhi,
                            float* __restrict__ xk, unsigned short* __restrict__ khi,
                            const float* __restrict__ alpha,
                            unsigned int* __restrict__ maxhh_u, int* __restrict__ cnt)
{
    int r = blockIdx.x * blockDim.x + threadIdx.x;
    float* p;
    unsigned short* dhi;
    float sgn = 1.f;
    if (r < MHEAD * LQ) {
        maxhh_u[r] = 0u;      // 0 < any ord-encoded float
        cnt[r] = 0;
        p   = xq + (size_t)r * CH;
        dhi = qhi + (size_t)r * CH;
        if (alpha[0] < 0.f) sgn = -1.f;
    } else {
        r -= MHEAD * LQ;
        p   = xk + (size_t)r * CH;
        dhi = khi + (size_t)r * CH;
    }

    float4 v[8];
    float ss = 0.f;
    #pragma unroll
    for (int i = 0; i < 8; ++i) {
        v[i] = *(const float4*)(p + i * 4);
        ss = fmaf(v[i].x, v[i].x, ss);
        ss = fmaf(v[i].y, v[i].y, ss);
        ss = fmaf(v[i].z, v[i].z, ss);
        ss = fmaf(v[i].w, v[i].w, ss);
    }
    const float inv = sgn / fmaxf(sqrtf(ss), 1e-12f);

    ushort8v hb[4];
    #pragma unroll
    for (int i = 0; i < 8; ++i) {
        float4 w;
        w.x = v[i].x * inv; w.y = v[i].y * inv;
        w.z = v[i].z * inv; w.w = v[i].w * inv;
        *(float4*)(p + i * 4) = w;
        hb[i >> 1][(i & 1) * 4 + 0] = f32_to_bf16_bits(w.x);
        hb[i >> 1][(i & 1) * 4 + 1] = f32_to_bf16_bits(w.y);
        hb[i >> 1][(i & 1) * 4 + 2] = f32_to_bf16_bits(w.z);
        hb[i >> 1][(i & 1) * 4 + 3] = f32_to_bf16_bits(w.w);
    }
    #pragma unroll
    for (int i = 0; i < 4; ++i)
        *(ushort8v*)(dhi + i * 8) = hb[i];
}

// ------------------------------------------------------------------
// Pass A1 (R8-proven: s-split x4, 512-row chunks, 16 iters/block so
// the depth-2 prefetch reaches steady state). 32 q-rows/wave, two
// 32-row k-tiles/iter, v_max3 fold, global atomicMax merge.
// Grid: 32 heads * 16 qb * 4 sc = 2048 blocks.
// ------------------------------------------------------------------
__global__ __launch_bounds__(256, 4)
void maxpass_kernel(const unsigned short* __restrict__ qhi,
                    const unsigned short* __restrict__ khi,
                    unsigned int* __restrict__ maxhh_u)
{
    const int b    = blockIdx.x;
    const int sc   = b & 3;
    const int qb   = (b >> 2) & 15;
    const int h    = b >> 6;
    const int wave = threadIdx.x >> 6;
    const int lane = threadIdx.x & 63;
    const int qbase = qb * 128 + wave * 32;
    const int col   = lane & 31;
    const int g8    = (lane >> 5) * 8;

    const size_t qoff = ((size_t)h * LQ + qbase + col) * CH + g8;
    const bf16x8 ah0 = *(const bf16x8*)(qhi + qoff);
    const bf16x8 ah1 = *(const bf16x8*)(qhi + qoff + 16);

    const unsigned short* kh = khi + ((size_t)h * SK + sc * 512) * CH;
    const size_t koff = (size_t)col * CH + g8;

    float maxv[16];
    #pragma unroll
    for (int r = 0; r < 16; ++r) maxv[r] = -INFINITY;

    bf16x8 t0a = *(const bf16x8*)(kh + koff);
    bf16x8 t0b = *(const bf16x8*)(kh + koff + 16);
    bf16x8 t1a = *(const bf16x8*)(kh + koff + 32 * CH);
    bf16x8 t1b = *(const bf16x8*)(kh + koff + 32 * CH + 16);

    for (int sb = 0; sb < 16; sb += 2) {
        const bf16x8 c0a = t0a, c0b = t0b, c1a = t1a, c1b = t1b;
        if (sb + 2 < 16) {
            const size_t o = koff + (size_t)(sb + 2) * 32 * CH;
            t0a = *(const bf16x8*)(kh + o);
            t0b = *(const bf16x8*)(kh + o + 16);
            t1a = *(const bf16x8*)(kh + o + 32 * CH);
            t1b = *(const bf16x8*)(kh + o + 32 * CH + 16);
        }
        f32x16 c = {0.f, 0.f, 0.f, 0.f, 0.f, 0.f, 0.f, 0.f,
                    0.f, 0.f, 0.f, 0.f, 0.f, 0.f, 0.f, 0.f};
        c = MFMA32(ah0, c0a, c);
        c = MFMA32(ah1, c0b, c);
        f32x16 d = {0.f, 0.f, 0.f, 0.f, 0.f, 0.f, 0.f, 0.f,
                    0.f, 0.f, 0.f, 0.f, 0.f, 0.f, 0.f, 0.f};
        d = MFMA32(ah0, c1a, d);
        d = MFMA32(ah1, c1b, d);
        #pragma unroll
        for (int r = 0; r < 16; ++r)
            maxv[r] = fmaxf(maxv[r], fmaxf(c[r], d[r]));   // -> v_max3_f32
    }

    #pragma unroll
    for (int r = 0; r < 16; ++r) {
        float v = maxv[r];
        #pragma unroll
        for (int m = 16; m >= 1; m >>= 1)
            v = fmaxf(v, __shfl_xor(v, m, 64));
        maxv[r] = v;
    }
    if (col == 0) {
        const int rbase = h * LQ + qbase + 4 * (lane >> 5);
        #pragma unroll
        for (int r = 0; r < 16; ++r)
            atomicMax(&maxhh_u[rbase + (r & 3) + 8 * (r >> 2)], ord_encode(maxv[r]));
    }
}

// ------------------------------------------------------------------
// Pass A2 (R8-proven): append s with hh >= globalmax - MARGIN.
// Hit-mask fast path. Grid: 2048 blocks.
// ------------------------------------------------------------------
__global__ __launch_bounds__(256, 4)
void candpass_kernel(const unsigned short* __restrict__ qhi,
                     const unsigned short* __restrict__ khi,
                     const unsigned int* __restrict__ maxhh_u,
                     int* __restrict__ cnt, int* __restrict__ cand)
{
    const int b    = blockIdx.x;
    const int sc   = b & 3;
    const int qb   = (b >> 2) & 15;
    const int h    = b >> 6;
    const int wave = threadIdx.x >> 6;
    const int lane = threadIdx.x & 63;
    const int qbase = qb * 128 + wave * 32;
    const int col   = lane & 31;
    const int g8    = (lane >> 5) * 8;

    const size_t qoff = ((size_t)h * LQ + qbase + col) * CH + g8;
    const bf16x8 ah0 = *(const bf16x8*)(qhi + qoff);
    const bf16x8 ah1 = *(const bf16x8*)(qhi + qoff + 16);

    int   rows[16];
    float thr[16];
    {
        const int rbase = h * LQ + qbase + 4 * (lane >> 5);
        #pragma unroll
        for (int r = 0; r < 16; ++r) {
            rows[r] = rbase + (r & 3) + 8 * (r >> 2);
            thr[r]  = ord_decode(maxhh_u[rows[r]]) - MARGIN;
        }
    }

    const unsigned short* kh = khi + ((size_t)h * SK + sc * 512) * CH;
    const size_t koff = (size_t)col * CH + g8;
    const int sbase = sc * 512;

    bf16x8 t0a = *(const bf16x8*)(kh + koff);
    bf16x8 t0b = *(const bf16x8*)(kh + koff + 16);
    bf16x8 t1a = *(const bf16x8*)(kh + koff + 32 * CH);
    bf16x8 t1b = *(const bf16x8*)(kh + koff + 32 * CH + 16);

    for (int sb = 0; sb < 16; sb += 2) {
        const bf16x8 c0a = t0a, c0b = t0b, c1a = t1a, c1b = t1b;
        if (sb + 2 < 16) {
            const size_t o = koff + (size_t)(sb + 2) * 32 * CH;
            t0a = *(const bf16x8*)(kh + o);
            t0b = *(const bf16x8*)(kh + o + 16);
            t1a = *(const bf16x8*)(kh + o + 32 * CH);
            t1b = *(const bf16x8*)(kh + o + 32 * CH + 16);
        }
        f32x16 c = {0.f, 0.f, 0.f, 0.f, 0.f, 0.f, 0.f, 0.f,
                    0.f, 0.f, 0.f, 0.f, 0.f, 0.f, 0.f, 0.f};
        c = MFMA32(ah0, c0a, c);
        c = MFMA32(ah1, c0b, c);
        f32x16 d = {0.f, 0.f, 0.f, 0.f, 0.f, 0.f, 0.f, 0.f,
                    0.f, 0.f, 0.f, 0.f, 0.f, 0.f, 0.f, 0.f};
        d = MFMA32(ah0, c1a, d);
        d = MFMA32(ah1, c1b, d);

        unsigned int hit = 0u;
        #pragma unroll
        for (int r = 0; r < 16; ++r) {
            const float e = fmaxf(c[r], d[r]);
            hit = (e >= thr[r]) ? (hit | (1u << r)) : hit;
        }
        if (hit) {
            const int s0 = sbase + sb * 32 + col;
            #pragma unroll
            for (int r = 0; r < 16; ++r) {
                if (hit & (1u << r)) {
                    if (c[r] >= thr[r]) {
                        const int slot = atomicAdd(&cnt[rows[r]], 1);
                        if (slot < CAP) cand[(size_t)rows[r] * CAP + slot] = s0;
                    }
                    if (d[r] >= thr[r]) {
                        const int slot = atomicAdd(&cnt[rows[r]], 1);
                        if (slot < CAP) cand[(size_t)rows[r] * CAP + slot] = s0 + 32;
                    }
                }
            }
        }
    }
}

// ------------------------------------------------------------------
// Pass B: exact f32 refine (chain bit-identical to R2) + sigmoid +
// gather + scale; writes new_x0 as bf16 for the MFMA output GEMM.
// ------------------------------------------------------------------
__global__ __launch_bounds__(256)
void refine_gather_kernel(const float* __restrict__ qn,
                          const float* __restrict__ kn,
                          const int* __restrict__ cnt, const int* __restrict__ cand,
                          const float* __restrict__ xv,
                          const float* __restrict__ alpha, const float* __restrict__ beta,
                          unsigned short* __restrict__ nxb)  // (4,2048,256) bf16
{
    const int r = blockIdx.x * blockDim.x + threadIdx.x;  // h*2048 + l
    const int h = r >> 11, l = r & 2047;

    float qr[CH];
    #pragma unroll
    for (int i = 0; i < 8; ++i) {
        const float4 v = *(const float4*)(qn + (size_t)r * CH + i * 4);
        qr[i * 4 + 0] = v.x; qr[i * 4 + 1] = v.y;
        qr[i * 4 + 2] = v.z; qr[i * 4 + 3] = v.w;
    }

    int m = cnt[r];
    if (m > CAP) m = CAP;
    float best = -INFINITY;
    int   bidx = 0x7fffffff;
    for (int j = 0; j < m; ++j) {
        const int s = cand[(size_t)r * CAP + j];
        const float4* k4 = (const float4*)(kn + ((size_t)h * SK + s) * CH);
        float p = 0.f;
        #pragma unroll
        for (int c = 0; c < 8; ++c) {
            const float4 kv = k4[c];
            p = fmaf(qr[c * 4 + 0], kv.x, p);
            p = fmaf(qr[c * 4 + 1], kv.y, p);
            p = fmaf(qr[c * 4 + 2], kv.z, p);
            p = fmaf(qr[c * 4 + 3], kv.w, p);
        }
        if (p > best || (p == best && s < bidx)) { best = p; bidx = s; }
    }
    if (bidx == 0x7fffffff) bidx = 0;   // unreachable guard

    const float a = alpha[0], be = beta[0];
    float tv;
    int idx = bidx;
    if (a == 0.f) { idx = 0; tv = be; }
    else          { tv = fmaf(fabsf(a), best, be); }
    float val;
    if (tv >= 0.f) val = 1.f / (1.f + expf(-tv));
    else           { const float e = expf(tv); val = e / (1.f + e); }

    const float4* vr = (const float4*)(xv + ((size_t)h * SK + idx) * CH);
    const int n = h >> 3, f = h & 7;
    unsigned short* out = nxb + (((size_t)n * LQ + l) * (FC * CH)) + f * CH;
    #pragma unroll
    for (int i = 0; i < 8; ++i) {
        const float4 w = vr[i];
        ushort8v o;
        o[0] = f32_to_bf16_bits(w.x * val);
        o[1] = f32_to_bf16_bits(w.y * val);
        o[2] = f32_to_bf16_bits(w.z * val);
        o[3] = f32_to_bf16_bits(w.w * val);
        *(unsigned long long*)(out + i * 4) = __builtin_bit_cast(unsigned long long,
            *(const ulong1*)&o);
    }
}

// ------------------------------------------------------------------
// K6: out = nx(bf16) @ Wm(bf16 swizzled) + bm, f32 out. MFMA 32x32.
// ------------------------------------------------------------------
__global__ __launch_bounds__(256)
void gemm_out_mfma_kernel(const unsigned short* __restrict__ nxb,
                          const unsigned short* __restrict__ wm_s,
                          const float* __restrict__ bm, float* __restrict__ out)
{
    const int wave = threadIdx.x >> 6;
    const int lane = threadIdx.x & 63;
    const int idx  = blockIdx.x * 4 + wave;
    const int mt   = idx >> 3;
    const int nt   = idx & 7;
    const int col  = lane & 31;
    const int g8   = (lane >> 5) * 8;

    const unsigned short* aptr = nxb + (size_t)(mt * 32 + col) * 256 + g8;
    const unsigned short* bptr = wm_s + nt * 32 * 16 + col * 16 + g8;

    f32x16 acc = {0.f, 0.f, 0.f, 0.f, 0.f, 0.f, 0.f, 0.f,
                  0.f, 0.f, 0.f, 0.f, 0.f, 0.f, 0.f, 0.f};
    #pragma unroll 4
    for (int kc = 0; kc < 16; ++kc) {
        const bf16x8 a = *(const bf16x8*)(aptr + kc * 16);
        const bf16x8 bfr = *(const bf16x8*)(bptr + (size_t)kc * 4096);
        acc = MFMA32(a, bfr, acc);
    }

    const int n0 = nt * 32;
    const float bias = bm[n0 + col];
    #pragma unroll
    for (int r = 0; r < 16; ++r) {
        const int row = mt * 32 + (r & 3) + 8 * (r >> 2) + 4 * (lane >> 5);
        out[(size_t)row * 256 + n0 + col] = acc[r] + bias;
    }
}

// ------------------------------------------------------------------
extern "C" void kernel_launch(void* const* d_in, const int* in_sizes, int n_in,
                              void* d_out, int out_size, void* d_ws, size_t ws_size,
                              hipStream_t stream)
{
    const float* x0 = (const float*)d_in[0];
    const float* x1 = (const float*)d_in[1];
    const float* W0 = (const float*)d_in[2];
    const float* b0 = (const float*)d_in[3];
    const float* W1 = (const float*)d_in[4];
    const float* b1 = (const float*)d_in[5];
    const float* Wm = (const float*)d_in[6];
    const float* bm = (const float*)d_in[7];
    const float* alpha = (const float*)d_in[8];
    const float* beta  = (const float*)d_in[9];
    float* out = (float*)d_out;

    char* ws = (char*)d_ws;
    const size_t MB = 1024ull * 1024ull;
    float* x0q = (float*)(ws + 0);          // (32,2048,32) f32, normalized in place
    float* x1k = (float*)(ws + 8 * MB);     // (32,2048,32) f32, normalized in place
    float* x1v = (float*)(ws + 16 * MB);    // (32,2048,32) f32 values
    unsigned short* qhi = (unsigned short*)(ws + 24 * MB);  // 4MB (dead after scan)
    unsigned short* khi = (unsigned short*)(ws + 28 * MB);  // 4MB
    unsigned short* x1b = (unsigned short*)(ws + 32 * MB);  // 4MB (dead after valgemm)
    int* cand = (int*)(ws + 32 * MB);       // 4MB CAP16 (reuses x1b; valgemm reads
                                            // x1b before candpass writes cand)
    unsigned int* maxhh_u = (unsigned int*)(ws + 36 * MB);          // 256KB
    int* cnt  = (int*)(ws + 36 * MB + 256 * 1024);                  // 256KB
    unsigned short* wm_s = (unsigned short*)(ws + 36 * MB + 512 * 1024); // 128KB
    unsigned short* wv_s = (unsigned short*)(ws + 36 * MB + 640 * 1024); // 128KB
    unsigned short* nxb  = (unsigned short*)(ws + 24 * MB); // reuse qhi region

    const int Mrows = NB * LQ;   // 8192

    // 1) exact-f32 projections: q + k-point (argmax path, bit-stable)
    proj_gemm_kernel<<<dim3(8, Mrows / 64), 256, 0, stream>>>(
        x0, x1, W0, b0, W1, b1, x0q, x1k);
    // 2) preps: x1->bf16, Wm & W1-value -> swizzled bf16
    prep_kernel<<<1536, 256, 0, stream>>>(x1, Wm, W1, x1b, wm_s, wv_s);
    // 3) value projection via bf16 MFMA
    val_gemm_kernel<<<512, 256, 0, stream>>>(x1b, wv_s, b1, x1v);
    // 4) normalize q+k in place + bf16 hi copies + zero maxhh/cnt
    norm_split_init_kernel<<<(2 * MHEAD * LQ) / 256, 256, 0, stream>>>(
        x0q, qhi, x1k, khi, alpha, maxhh_u, cnt);
    // 5) global hh max (R8-proven x4 split, 512-row chunks)
    maxpass_kernel<<<2048, 256, 0, stream>>>(qhi, khi, maxhh_u);
    // 6) candidate collection vs global threshold (x4 split)
    candpass_kernel<<<2048, 256, 0, stream>>>(qhi, khi, maxhh_u, cnt, cand);
    // 7) exact refine + sigmoid + gather + scale -> bf16 nx
    refine_gather_kernel<<<(MHEAD * LQ) / 256, 256, 0, stream>>>(
        x0q, x1k, cnt, cand, x1v, alpha, beta, nxb);
    // 8) out = nx @ Wm + bm via bf16 MFMA
    gemm_out_mfma_kernel<<<512, 256, 0, stream>>>(nxb, wm_s, bm, out);
}

// Round 13
// 134.815 us; speedup vs baseline: 1.4107x; 1.0356x over previous
//
#include <hip/hip_runtime.h>
#include <hip/hip_bf16.h>
#include <cmath>

// Problem constants (fixed by reference)
#define NB   4      // batch
#define LQ   2048   // query len
#define SK   2048   // source len
#define DD   256    // in depth
#define HD   256    // hidden
#define FC   8      // heads
#define CH   32     // channels per head (HD/FC)
#define MHEAD 32    // NB*FC

// hh-filter margin: |f32dot - bf16dot| <= 2*2^-9 per side (unit rows) + slack
#define MARGIN 0.0085f
#define CAP    16   // candidate slots per row (avg ~1.2 with global threshold)

// LDS K staging: 128-row groups, rows padded to 80B (40 shorts) so the
// b128 reads spread over 8 bank-slots (4-way conflict = 1.58x, m136).
#define KROW 40     // shorts per padded row

typedef float f32x16 __attribute__((ext_vector_type(16)));
typedef float f32x2  __attribute__((ext_vector_type(2)));
typedef short bf16x8 __attribute__((ext_vector_type(8)));
typedef unsigned short ushort8v __attribute__((ext_vector_type(8)));

__device__ inline unsigned short f32_to_bf16_bits(float v) {
    __hip_bfloat16 b = __float2bfloat16(v);   // round-to-nearest
    return __builtin_bit_cast(unsigned short, b);
}
__device__ inline unsigned int ord_encode(float v) {
    unsigned int u = __float_as_uint(v);
    return (u & 0x80000000u) ? ~u : (u | 0x80000000u);
}
__device__ inline float ord_decode(unsigned int e) {
    unsigned int u = (e & 0x80000000u) ? (e & 0x7fffffffu) : ~e;
    return __uint_as_float(u);
}

#define MFMA32(a, b, c) __builtin_amdgcn_mfma_f32_32x32x16_bf16(a, b, c, 0, 0, 0)

// ------------------------------------------------------------------
// Exact-f32 projection GEMM (R12-proven): q (W0) + k-point (W1 point
// cols). 64x64 tile, 4x4/thread, LDS dbuf, pk-fma, unified epilogue.
// Only change vs R12: the two b64 B-reads merged into one float4 read
// (same values, same FMA order -> bit-identical outputs).
// ------------------------------------------------------------------
__global__ __launch_bounds__(256, 7)
void proj_gemm_kernel(const float* __restrict__ x0, const float* __restrict__ x1,
                      const float* __restrict__ W0, const float* __restrict__ b0f,
                      const float* __restrict__ W1, const float* __restrict__ b1f,
                      float* __restrict__ xq, float* __restrict__ xk)
{
    __shared__ float As[2][16][68];
    __shared__ float Bs[2][16][64];
    const int nt  = blockIdx.x;        // 0..7 (wave-uniform branch)
    const bool is0 = (nt < 4);
    const float* A    = is0 ? x0 : x1;
    const float* B    = is0 ? W0 : W1;
    const float* bias = is0 ? b0f : b1f;
    float* dst        = is0 ? xq : xk;
    const int NB_ = is0 ? HD : 2 * HD;   // B row stride
    const int hw  = is0 ? 32 : 64;       // per-head column stride in B/bias
    const int bm  = blockIdx.y * 64;
    const int K   = DD;

    const int tx = threadIdx.x & 15;
    const int ty = threadIdx.x >> 4;
    f32x2 acc2[4][2] = {};

    const int arow = threadIdx.x >> 2;           // 0..63
    const int akq  = (threadIdx.x & 3) << 2;     // 0,4,8,12
    const int bkr  = threadIdx.x >> 4;           // 0..15
    const int bnq  = (threadIdx.x & 15) << 2;    // 0..60
    const int fl   = (nt & 3) * 2 + (bnq >> 5);  // head of loaded cols
    const int bcol = fl * hw + (bnq & 31);

    {
        const float4 a4 = *(const float4*)&A[(size_t)(bm + arow) * K + akq];
        const float4 b4 = *(const float4*)&B[(size_t)bkr * NB_ + bcol];
        As[0][akq + 0][arow] = a4.x;
        As[0][akq + 1][arow] = a4.y;
        As[0][akq + 2][arow] = a4.z;
        As[0][akq + 3][arow] = a4.w;
        *(float4*)&Bs[0][bkr][bnq] = b4;
    }
    __syncthreads();

    const int nchunk = K >> 4;   // 16
    float4 pa, pb;
    for (int c = 0; c < nchunk; ++c) {
        const int cur = c & 1;
        if (c + 1 < nchunk) {
            const int k0 = (c + 1) << 4;
            pa = *(const float4*)&A[(size_t)(bm + arow) * K + k0 + akq];
            pb = *(const float4*)&B[(size_t)(k0 + bkr) * NB_ + bcol];
        }
        #pragma unroll
        for (int kk = 0; kk < 16; ++kk) {
            const float4 a4 = *(const float4*)&As[cur][kk][ty << 2];
            const float4 bv = *(const float4*)&Bs[cur][kk][tx << 2];
            const f32x2 b01 = {bv.x, bv.y};
            const f32x2 b23 = {bv.z, bv.w};
            const float av[4] = {a4.x, a4.y, a4.z, a4.w};
            #pragma unroll
            for (int i = 0; i < 4; ++i) {
                const f32x2 aa = {av[i], av[i]};
                acc2[i][0] = __builtin_elementwise_fma(aa, b01, acc2[i][0]);
                acc2[i][1] = __builtin_elementwise_fma(aa, b23, acc2[i][1]);
            }
        }
        if (c + 1 < nchunk) {
            const int nxt = cur ^ 1;
            As[nxt][akq + 0][arow] = pa.x;
            As[nxt][akq + 1][arow] = pa.y;
            As[nxt][akq + 2][arow] = pa.z;
            As[nxt][akq + 3][arow] = pa.w;
            *(float4*)&Bs[nxt][bkr][bnq] = pb;
        }
        __syncthreads();
    }

    #pragma unroll
    for (int i = 0; i < 4; ++i) {
        const int row = bm + (ty << 2) + i;
        const int n = row >> 11, l = row & 2047;
        #pragma unroll
        for (int j = 0; j < 4; ++j) {
            const int cl = (tx << 2) + j;
            const int f  = (nt & 3) * 2 + (cl >> 5);
            const int cc = cl & 31;
            const float v = acc2[i][j >> 1][j & 1] + bias[f * hw + cc];
            dst[((((size_t)n * FC + f) * LQ) + l) * CH + cc] = v;
        }
    }
}

// ------------------------------------------------------------------
// Prep: x1 -> bf16 rows; Wm and W1-value cols -> bf16 B-frag swizzle.
// ------------------------------------------------------------------
__global__ __launch_bounds__(256)
void prep_kernel(const float* __restrict__ x1, const float* __restrict__ Wm,
                 const float* __restrict__ W1,
                 unsigned short* __restrict__ x1b,
                 unsigned short* __restrict__ wm_s,
                 unsigned short* __restrict__ wv_s)
{
    const int i = blockIdx.x * 256 + threadIdx.x;
    if (i < 262144) {
        const float4 a = *(const float4*)(x1 + (size_t)i * 8);
        const float4 b = *(const float4*)(x1 + (size_t)i * 8 + 4);
        ushort8v o;
        o[0] = f32_to_bf16_bits(a.x); o[1] = f32_to_bf16_bits(a.y);
        o[2] = f32_to_bf16_bits(a.z); o[3] = f32_to_bf16_bits(a.w);
        o[4] = f32_to_bf16_bits(b.x); o[5] = f32_to_bf16_bits(b.y);
        o[6] = f32_to_bf16_bits(b.z); o[7] = f32_to_bf16_bits(b.w);
        *(ushort8v*)(x1b + (size_t)i * 8) = o;
    } else if (i < 262144 + 65536) {
        const int j = i - 262144;
        const int k = j >> 8, n = j & 255;
        wm_s[(k >> 4) * 4096 + n * 16 + (k & 15)] = f32_to_bf16_bits(Wm[k * 256 + n]);
    } else {
        const int j = i - 327680;
        const int k = j >> 8, v = j & 255;
        const int w = (v >> 5) * 64 + 32 + (v & 31);
        wv_s[(k >> 4) * 4096 + v * 16 + (k & 15)] = f32_to_bf16_bits(W1[k * 512 + w]);
    }
}

// ------------------------------------------------------------------
// Value projection via bf16 MFMA: x1v = x1 @ W1value + b1value.
// ------------------------------------------------------------------
__global__ __launch_bounds__(256)
void val_gemm_kernel(const unsigned short* __restrict__ x1b,
                     const unsigned short* __restrict__ wv_s,
                     const float* __restrict__ b1f, float* __restrict__ xv)
{
    const int wave = threadIdx.x >> 6;
    const int lane = threadIdx.x & 63;
    const int idx  = blockIdx.x * 4 + wave;
    const int mt   = idx >> 3;
    const int nt   = idx & 7;
    const int col  = lane & 31;
    const int g8   = (lane >> 5) * 8;

    const unsigned short* aptr = x1b + (size_t)(mt * 32 + col) * 256 + g8;
    const unsigned short* bptr = wv_s + nt * 32 * 16 + col * 16 + g8;

    f32x16 acc = {0.f, 0.f, 0.f, 0.f, 0.f, 0.f, 0.f, 0.f,
                  0.f, 0.f, 0.f, 0.f, 0.f, 0.f, 0.f, 0.f};
    #pragma unroll 4
    for (int kc = 0; kc < 16; ++kc) {
        const bf16x8 a = *(const bf16x8*)(aptr + kc * 16);
        const bf16x8 bfr = *(const bf16x8*)(bptr + (size_t)kc * 4096);
        acc = MFMA32(a, bfr, acc);
    }

    const int v = nt * 32 + col;
    const int f = v >> 5, c = v & 31;
    const float bias = b1f[f * 64 + 32 + c];
    #pragma unroll
    for (int r = 0; r < 16; ++r) {
        const int g = mt * 32 + (r & 3) + 8 * (r >> 2) + 4 * (lane >> 5);
        const int n = g >> 11, s = g & 2047;
        xv[((((size_t)n * FC + f) * SK) + s) * CH + c] = acc[r] + bias;
    }
}

// ------------------------------------------------------------------
// Combined: L2-normalize q+k rows in place (bit-identical to R2),
// emit bf16 hi copies, zero-init maxhh_u and cnt.
// ------------------------------------------------------------------
__global__ __launch_bounds__(256)
void norm_split_init_kernel(float* __restrict__ xq, unsigned short* __restrict__ qhi,
                            float* __restrict__ xk, unsigned short* __restrict__ khi,
                            const float* __restrict__ alpha,
                            unsigned int* __restrict__ maxhh_u, int* __restrict__ cnt)
{
    int r = blockIdx.x * blockDim.x + threadIdx.x;
    float* p;
    unsigned short* dhi;
    float sgn = 1.f;
    if (r < MHEAD * LQ) {
        maxhh_u[r] = 0u;      // 0 < any ord-encoded float
        cnt[r] = 0;
        p   = xq + (size_t)r * CH;
        dhi = qhi + (size_t)r * CH;
        if (alpha[0] < 0.f) sgn = -1.f;
    } else {
        r -= MHEAD * LQ;
        p   = xk + (size_t)r * CH;
        dhi = khi + (size_t)r * CH;
    }

    float4 v[8];
    float ss = 0.f;
    #pragma unroll
    for (int i = 0; i < 8; ++i) {
        v[i] = *(const float4*)(p + i * 4);
        ss = fmaf(v[i].x, v[i].x, ss);
        ss = fmaf(v[i].y, v[i].y, ss);
        ss = fmaf(v[i].z, v[i].z, ss);
        ss = fmaf(v[i].w, v[i].w, ss);
    }
    const float inv = sgn / fmaxf(sqrtf(ss), 1e-12f);

    ushort8v hb[4];
    #pragma unroll
    for (int i = 0; i < 8; ++i) {
        float4 w;
        w.x = v[i].x * inv; w.y = v[i].y * inv;
        w.z = v[i].z * inv; w.w = v[i].w * inv;
        *(float4*)(p + i * 4) = w;
        hb[i >> 1][(i & 1) * 4 + 0] = f32_to_bf16_bits(w.x);
        hb[i >> 1][(i & 1) * 4 + 1] = f32_to_bf16_bits(w.y);
        hb[i >> 1][(i & 1) * 4 + 2] = f32_to_bf16_bits(w.z);
        hb[i >> 1][(i & 1) * 4 + 3] = f32_to_bf16_bits(w.w);
    }
    #pragma unroll
    for (int i = 0; i < 4; ++i)
        *(ushort8v*)(dhi + i * 8) = hb[i];
}

// ------------------------------------------------------------------
// Pass A1 v4: LDS-staged K. Block scans its 512-row chunk as 4 groups
// of 128 rows; K staged cooperatively into double-buffered LDS (one
// barrier per group; loads for g+1 issued before computing g). All 4
// waves read the SAME staged tiles (was: 4x redundant global streams
// with only ~180cyc load->use slack -> latency-bound, occ 17%).
// Values identical to R12's scan -> same maxes bit-for-bit.
// Grid: 32 heads * 16 qb * 4 sc = 2048 blocks.
// ------------------------------------------------------------------
__global__ __launch_bounds__(256, 4)
void maxpass_kernel(const unsigned short* __restrict__ qhi,
                    const unsigned short* __restrict__ khi,
                    unsigned int* __restrict__ maxhh_u)
{
    __shared__ unsigned short kbuf[2][128 * KROW];   // 2 x 10240B
    const int b    = blockIdx.x;
    const int sc   = b & 3;
    const int qb   = (b >> 2) & 15;
    const int h    = b >> 6;
    const int wave = threadIdx.x >> 6;
    const int lane = threadIdx.x & 63;
    const int t    = threadIdx.x;
    const int qbase = qb * 128 + wave * 32;
    const int col   = lane & 31;
    const int g8    = (lane >> 5) * 8;

    const size_t qoff = ((size_t)h * LQ + qbase + col) * CH + g8;
    const bf16x8 ah0 = *(const bf16x8*)(qhi + qoff);
    const bf16x8 ah1 = *(const bf16x8*)(qhi + qoff + 16);

    const unsigned short* kh = khi + ((size_t)h * SK + sc * 512) * CH;

    // staging: thread t owns row t>>1, 16-short half t&1 of each group
    const int srow  = t >> 1;
    const int shalf = (t & 1) * 16;
    const unsigned short* sp = kh + (size_t)srow * CH + shalf;

    float maxv[16];
    #pragma unroll
    for (int r = 0; r < 16; ++r) maxv[r] = -INFINITY;

    // prologue: stage group 0
    bf16x8 s0 = *(const bf16x8*)(sp);
    bf16x8 s1 = *(const bf16x8*)(sp + 8);
    *(bf16x8*)(&kbuf[0][srow * KROW + shalf])     = s0;
    *(bf16x8*)(&kbuf[0][srow * KROW + shalf + 8]) = s1;
    __syncthreads();

    for (int g = 0; g < 4; ++g) {
        if (g < 3) {
            const unsigned short* spn = sp + (size_t)(g + 1) * 128 * CH;
            s0 = *(const bf16x8*)(spn);
            s1 = *(const bf16x8*)(spn + 8);
        }
        const unsigned short* kbp = &kbuf[g & 1][0];
        #pragma unroll
        for (int tt = 0; tt < 4; ++tt) {
            const int rl = tt * 32 + col;
            const bf16x8 ka  = *(const bf16x8*)(kbp + rl * KROW + g8);
            const bf16x8 kbv = *(const bf16x8*)(kbp + rl * KROW + 16 + g8);
            f32x16 c = {0.f, 0.f, 0.f, 0.f, 0.f, 0.f, 0.f, 0.f,
                        0.f, 0.f, 0.f, 0.f, 0.f, 0.f, 0.f, 0.f};
            c = MFMA32(ah0, ka, c);
            c = MFMA32(ah1, kbv, c);
            #pragma unroll
            for (int r = 0; r < 16; ++r) maxv[r] = fmaxf(maxv[r], c[r]);
        }
        if (g < 3) {
            unsigned short* swn = &kbuf[(g + 1) & 1][srow * KROW + shalf];
            *(bf16x8*)(swn)     = s0;
            *(bf16x8*)(swn + 8) = s1;
            __syncthreads();
        }
    }

    #pragma unroll
    for (int r = 0; r < 16; ++r) {
        float v = maxv[r];
        #pragma unroll
        for (int m = 16; m >= 1; m >>= 1)
            v = fmaxf(v, __shfl_xor(v, m, 64));
        maxv[r] = v;
    }
    if (col == 0) {
        const int rbase = h * LQ + qbase + 4 * (lane >> 5);
        #pragma unroll
        for (int r = 0; r < 16; ++r)
            atomicMax(&maxhh_u[rbase + (r & 3) + 8 * (r >> 2)], ord_encode(maxv[r]));
    }
}

// ------------------------------------------------------------------
// Pass A2 v4: same LDS-staged scan; append s with hh >= max - MARGIN.
// Candidate set identical to R12's (same hh values, same threshold).
// ------------------------------------------------------------------
__global__ __launch_bounds__(256, 4)
void candpass_kernel(const unsigned short* __restrict__ qhi,
                     const unsigned short* __restrict__ khi,
                     const unsigned int* __restrict__ maxhh_u,
                     int* __restrict__ cnt, int* __restrict__ cand)
{
    __shared__ unsigned short kbuf[2][128 * KROW];
    const int b    = blockIdx.x;
    const int sc   = b & 3;
    const int qb   = (b >> 2) & 15;
    const int h    = b >> 6;
    const int wave = threadIdx.x >> 6;
    const int lane = threadIdx.x & 63;
    const int t    = threadIdx.x;
    const int qbase = qb * 128 + wave * 32;
    const int col   = lane & 31;
    const int g8    = (lane >> 5) * 8;

    const size_t qoff = ((size_t)h * LQ + qbase + col) * CH + g8;
    const bf16x8 ah0 = *(const bf16x8*)(qhi + qoff);
    const bf16x8 ah1 = *(const bf16x8*)(qhi + qoff + 16);

    int   rows[16];
    float thr[16];
    {
        const int rbase = h * LQ + qbase + 4 * (lane >> 5);
        #pragma unroll
        for (int r = 0; r < 16; ++r) {
            rows[r] = rbase + (r & 3) + 8 * (r >> 2);
            thr[r]  = ord_decode(maxhh_u[rows[r]]) - MARGIN;
        }
    }

    const unsigned short* kh = khi + ((size_t)h * SK + sc * 512) * CH;
    const int sbase = sc * 512;

    const int srow  = t >> 1;
    const int shalf = (t & 1) * 16;
    const unsigned short* sp = kh + (size_t)srow * CH + shalf;

    bf16x8 s0 = *(const bf16x8*)(sp);
    bf16x8 s1 = *(const bf16x8*)(sp + 8);
    *(bf16x8*)(&kbuf[0][srow * KROW + shalf])     = s0;
    *(bf16x8*)(&kbuf[0][srow * KROW + shalf + 8]) = s1;
    __syncthreads();

    for (int g = 0; g < 4; ++g) {
        if (g < 3) {
            const unsigned short* spn = sp + (size_t)(g + 1) * 128 * CH;
            s0 = *(const bf16x8*)(spn);
            s1 = *(const bf16x8*)(spn + 8);
        }
        const unsigned short* kbp = &kbuf[g & 1][0];
        #pragma unroll
        for (int tt = 0; tt < 4; ++tt) {
            const int rl = tt * 32 + col;
            const bf16x8 ka  = *(const bf16x8*)(kbp + rl * KROW + g8);
            const bf16x8 kbv = *(const bf16x8*)(kbp + rl * KROW + 16 + g8);
            f32x16 c = {0.f, 0.f, 0.f, 0.f, 0.f, 0.f, 0.f, 0.f,
                        0.f, 0.f, 0.f, 0.f, 0.f, 0.f, 0.f, 0.f};
            c = MFMA32(ah0, ka, c);
            c = MFMA32(ah1, kbv, c);

            unsigned int hit = 0u;
            #pragma unroll
            for (int r = 0; r < 16; ++r)
                hit = (c[r] >= thr[r]) ? (hit | (1u << r)) : hit;
            if (hit) {
                const int s = sbase + g * 128 + tt * 32 + col;
                #pragma unroll
                for (int r = 0; r < 16; ++r) {
                    if (hit & (1u << r)) {
                        const int slot = atomicAdd(&cnt[rows[r]], 1);
                        if (slot < CAP) cand[(size_t)rows[r] * CAP + slot] = s;
                    }
                }
            }
        }
        if (g < 3) {
            unsigned short* swn = &kbuf[(g + 1) & 1][srow * KROW + shalf];
            *(bf16x8*)(swn)     = s0;
            *(bf16x8*)(swn + 8) = s1;
            __syncthreads();
        }
    }
}

// ------------------------------------------------------------------
// Pass B: exact f32 refine (chain bit-identical to R2) + sigmoid +
// gather + scale; writes new_x0 as bf16 for the MFMA output GEMM.
// ------------------------------------------------------------------
__global__ __launch_bounds__(256)
void refine_gather_kernel(const float* __restrict__ qn,
                          const float* __restrict__ kn,
                          const int* __restrict__ cnt, const int* __restrict__ cand,
                          const float* __restrict__ xv,
                          const float* __restrict__ alpha, const float* __restrict__ beta,
                          unsigned short* __restrict__ nxb)  // (4,2048,256) bf16
{
    const int r = blockIdx.x * blockDim.x + threadIdx.x;  // h*2048 + l
    const int h = r >> 11, l = r & 2047;

    float qr[CH];
    #pragma unroll
    for (int i = 0; i < 8; ++i) {
        const float4 v = *(const float4*)(qn + (size_t)r * CH + i * 4);
        qr[i * 4 + 0] = v.x; qr[i * 4 + 1] = v.y;
        qr[i * 4 + 2] = v.z; qr[i * 4 + 3] = v.w;
    }

    int m = cnt[r];
    if (m > CAP) m = CAP;
    float best = -INFINITY;
    int   bidx = 0x7fffffff;
    for (int j = 0; j < m; ++j) {
        const int s = cand[(size_t)r * CAP + j];
        const float4* k4 = (const float4*)(kn + ((size_t)h * SK + s) * CH);
        float p = 0.f;
        #pragma unroll
        for (int c = 0; c < 8; ++c) {
            const float4 kv = k4[c];
            p = fmaf(qr[c * 4 + 0], kv.x, p);
            p = fmaf(qr[c * 4 + 1], kv.y, p);
            p = fmaf(qr[c * 4 + 2], kv.z, p);
            p = fmaf(qr[c * 4 + 3], kv.w, p);
        }
        if (p > best || (p == best && s < bidx)) { best = p; bidx = s; }
    }
    if (bidx == 0x7fffffff) bidx = 0;   // unreachable guard

    const float a = alpha[0], be = beta[0];
    float tv;
    int idx = bidx;
    if (a == 0.f) { idx = 0; tv = be; }
    else          { tv = fmaf(fabsf(a), best, be); }
    float val;
    if (tv >= 0.f) val = 1.f / (1.f + expf(-tv));
    else           { const float e = expf(tv); val = e / (1.f + e); }

    const float4* vr = (const float4*)(xv + ((size_t)h * SK + idx) * CH);
    const int n = h >> 3, f = h & 7;
    unsigned short* out = nxb + (((size_t)n * LQ + l) * (FC * CH)) + f * CH;
    #pragma unroll
    for (int i = 0; i < 8; ++i) {
        const float4 w = vr[i];
        ushort8v o;
        o[0] = f32_to_bf16_bits(w.x * val);
        o[1] = f32_to_bf16_bits(w.y * val);
        o[2] = f32_to_bf16_bits(w.z * val);
        o[3] = f32_to_bf16_bits(w.w * val);
        *(unsigned long long*)(out + i * 4) = __builtin_bit_cast(unsigned long long,
            *(const ulong1*)&o);
    }
}

// ------------------------------------------------------------------
// K6: out = nx(bf16) @ Wm(bf16 swizzled) + bm, f32 out. MFMA 32x32.
// ------------------------------------------------------------------
__global__ __launch_bounds__(256)
void gemm_out_mfma_kernel(const unsigned short* __restrict__ nxb,
                          const unsigned short* __restrict__ wm_s,
                          const float* __restrict__ bm, float* __restrict__ out)
{
    const int wave = threadIdx.x >> 6;
    const int lane = threadIdx.x & 63;
    const int idx  = blockIdx.x * 4 + wave;
    const int mt   = idx >> 3;
    const int nt   = idx & 7;
    const int col  = lane & 31;
    const int g8   = (lane >> 5) * 8;

    const unsigned short* aptr = nxb + (size_t)(mt * 32 + col) * 256 + g8;
    const unsigned short* bptr = wm_s + nt * 32 * 16 + col * 16 + g8;

    f32x16 acc = {0.f, 0.f, 0.f, 0.f, 0.f, 0.f, 0.f, 0.f,
                  0.f, 0.f, 0.f, 0.f, 0.f, 0.f, 0.f, 0.f};
    #pragma unroll 4
    for (int kc = 0; kc < 16; ++kc) {
        const bf16x8 a = *(const bf16x8*)(aptr + kc * 16);
        const bf16x8 bfr = *(const bf16x8*)(bptr + (size_t)kc * 4096);
        acc = MFMA32(a, bfr, acc);
    }

    const int n0 = nt * 32;
    const float bias = bm[n0 + col];
    #pragma unroll
    for (int r = 0; r < 16; ++r) {
        const int row = mt * 32 + (r & 3) + 8 * (r >> 2) + 4 * (lane >> 5);
        out[(size_t)row * 256 + n0 + col] = acc[r] + bias;
    }
}

// ------------------------------------------------------------------
extern "C" void kernel_launch(void* const* d_in, const int* in_sizes, int n_in,
                              void* d_out, int out_size, void* d_ws, size_t ws_size,
                              hipStream_t stream)
{
    const float* x0 = (const float*)d_in[0];
    const float* x1 = (const float*)d_in[1];
    const float* W0 = (const float*)d_in[2];
    const float* b0 = (const float*)d_in[3];
    const float* W1 = (const float*)d_in[4];
    const float* b1 = (const float*)d_in[5];
    const float* Wm = (const float*)d_in[6];
    const float* bm = (const float*)d_in[7];
    const float* alpha = (const float*)d_in[8];
    const float* beta  = (const float*)d_in[9];
    float* out = (float*)d_out;

    char* ws = (char*)d_ws;
    const size_t MB = 1024ull * 1024ull;
    float* x0q = (float*)(ws + 0);          // (32,2048,32) f32, normalized in place
    float* x1k = (float*)(ws + 8 * MB);     // (32,2048,32) f32, normalized in place
    float* x1v = (float*)(ws + 16 * MB);    // (32,2048,32) f32 values
    unsigned short* qhi = (unsigned short*)(ws + 24 * MB);  // 4MB (dead after scan)
    unsigned short* khi = (unsigned short*)(ws + 28 * MB);  // 4MB
    unsigned short* x1b = (unsigned short*)(ws + 32 * MB);  // 4MB (dead after valgemm)
    int* cand = (int*)(ws + 32 * MB);       // 4MB CAP16 (reuses x1b; valgemm reads
                                            // x1b before candpass writes cand)
    unsigned int* maxhh_u = (unsigned int*)(ws + 36 * MB);          // 256KB
    int* cnt  = (int*)(ws + 36 * MB + 256 * 1024);                  // 256KB
    unsigned short* wm_s = (unsigned short*)(ws + 36 * MB + 512 * 1024); // 128KB
    unsigned short* wv_s = (unsigned short*)(ws + 36 * MB + 640 * 1024); // 128KB
    unsigned short* nxb  = (unsigned short*)(ws + 24 * MB); // reuse qhi region

    const int Mrows = NB * LQ;   // 8192

    // 1) exact-f32 projections: q + k-point (argmax path, bit-stable)
    proj_gemm_kernel<<<dim3(8, Mrows / 64), 256, 0, stream>>>(
        x0, x1, W0, b0, W1, b1, x0q, x1k);
    // 2) preps: x1->bf16, Wm & W1-value -> swizzled bf16
    prep_kernel<<<1536, 256, 0, stream>>>(x1, Wm, W1, x1b, wm_s, wv_s);
    // 3) value projection via bf16 MFMA
    val_gemm_kernel<<<512, 256, 0, stream>>>(x1b, wv_s, b1, x1v);
    // 4) normalize q+k in place + bf16 hi copies + zero maxhh/cnt
    norm_split_init_kernel<<<(2 * MHEAD * LQ) / 256, 256, 0, stream>>>(
        x0q, qhi, x1k, khi, alpha, maxhh_u, cnt);
    // 5) global hh max (LDS-staged K, x4 split)
    maxpass_kernel<<<2048, 256, 0, stream>>>(qhi, khi, maxhh_u);
    // 6) candidate collection vs global threshold (LDS-staged K)
    candpass_kernel<<<2048, 256, 0, stream>>>(qhi, khi, maxhh_u, cnt, cand);
    // 7) exact refine + sigmoid + gather + scale -> bf16 nx
    refine_gather_kernel<<<(MHEAD * LQ) / 256, 256, 0, stream>>>(
        x0q, x1k, cnt, cand, x1v, alpha, beta, nxb);
    // 8) out = nx @ Wm + bm via bf16 MFMA
    gemm_out_mfma_kernel<<<512, 256, 0, stream>>>(nxb, wm_s, bm, out);
}